// Round 12
// baseline (416.872 us; speedup 1.0000x reference)
//
#include <hip/hip_runtime.h>
#include <hip/hip_bf16.h>
#include <cmath>

#define N_ENT  50000
#define N_RELS 16
#define N_EDGE 1000000
#define DIM    64
#define OUT_STRIDE 176

typedef float f32x4 __attribute__((ext_vector_type(4)));
typedef short s16x8 __attribute__((ext_vector_type(8)));
typedef uint  u32x4 __attribute__((ext_vector_type(4)));

__device__ inline void bf16x8_unpack(uint4 u, float* f) {
    f[0] = __uint_as_float((u.x & 0xffffu) << 16);
    f[1] = __uint_as_float(u.x & 0xffff0000u);
    f[2] = __uint_as_float((u.y & 0xffffu) << 16);
    f[3] = __uint_as_float(u.y & 0xffff0000u);
    f[4] = __uint_as_float((u.z & 0xffffu) << 16);
    f[5] = __uint_as_float(u.z & 0xffff0000u);
    f[6] = __uint_as_float((u.w & 0xffffu) << 16);
    f[7] = __uint_as_float(u.w & 0xffff0000u);
}

__device__ inline ushort f2bf(float x) {
    __hip_bfloat16 b = __float2bfloat16(x);
    return *(ushort*)&b;
}

__device__ inline uint cvt_pk_bf16(float lo, float hi) {
    uint r;
    asm("v_cvt_pk_bf16_f32 %0, %1, %2" : "=v"(r) : "v"(lo), "v"(hi));
    return r;
}

// Column permutation for the packed-Z / ent_pi layout.
__device__ __host__ inline int pcol(int p) {
    int qp = (p >> 3) & 7;
    int k  = p & 7;
    return 16 * (k >> 1) + 2 * qp + (k & 1);
}

// ---------------------------------------------------------------------------
// K0a: streaming prep only — ent fp32 -> permuted bf16 table + out[:,0:64].
// ---------------------------------------------------------------------------
__global__ __launch_bounds__(256) void prep_convert_kernel(
        const float* __restrict__ ent,
        ushort* __restrict__ ent_pi,
        float* __restrict__ out) {
    int i = blockIdx.x * blockDim.x + threadIdx.x;
    if (i < N_ENT * DIM) {
        float v = ent[i];
        ushort b = f2bf(v);
        int n = i >> 6, c = i & 63;
        int pos = ((c & 15) >> 1) * 8 + ((c >> 4) << 1) + (c & 1);
        ent_pi[(size_t)n * 64 + pos] = b;
        out[(size_t)n * OUT_STRIDE + c] = v;
    }
}

// ---------------------------------------------------------------------------
// K2: 3-phase multi-block exclusive scan counts -> row_ptr
// ---------------------------------------------------------------------------
__global__ __launch_bounds__(256) void scan1_kernel(
        const int* __restrict__ counts, int* __restrict__ excl,
        int* __restrict__ bsum, int n) {
    __shared__ int sh[256];
    int t = threadIdx.x;
    int i = blockIdx.x * 256 + t;
    int c = (i < n) ? counts[i] : 0;
    sh[t] = c;
    __syncthreads();
    for (int off = 1; off < 256; off <<= 1) {
        int v = (t >= off) ? sh[t - off] : 0;
        __syncthreads();
        sh[t] += v;
        __syncthreads();
    }
    if (i < n) excl[i] = sh[t] - c;
    if (t == 255) bsum[blockIdx.x] = sh[255];
}

__global__ __launch_bounds__(256) void scan2_kernel(
        const int* __restrict__ bsum, int* __restrict__ boff,
        int* __restrict__ row_ptr, int nb, int n) {
    __shared__ int sh[256];
    int t = threadIdx.x;
    int v = (t < nb) ? bsum[t] : 0;
    sh[t] = v;
    __syncthreads();
    for (int off = 1; off < 256; off <<= 1) {
        int x = (t >= off) ? sh[t - off] : 0;
        __syncthreads();
        sh[t] += x;
        __syncthreads();
    }
    if (t < nb) boff[t] = sh[t] - v;
    if (t == nb - 1) row_ptr[n] = sh[t];
}

// K3: finalize row_ptr AND scatter per-edge info into CSR ORDER:
//   einfo[pos] = src(16b) | dst(16b)<<16 | rel(4b)<<32
__global__ __launch_bounds__(256) void scan3_pos_kernel(
        const int* __restrict__ excl, const int* __restrict__ boff,
        int* __restrict__ row_ptr,
        const int* __restrict__ src, const int* __restrict__ dst,
        const int* __restrict__ etype, const int* __restrict__ off,
        unsigned long long* __restrict__ einfo) {
    int i = blockIdx.x * blockDim.x + threadIdx.x;
    if (i < N_ENT) row_ptr[i] = excl[i] + boff[i >> 8];
    if (i < N_EDGE) {
        int d = dst[i];
        int pos = excl[d] + boff[d >> 8] + off[i];
        unsigned long long info =
              (unsigned long long)(unsigned)src[i]
            | ((unsigned long long)(unsigned)d << 16)
            | ((unsigned long long)(unsigned)etype[i] << 32);
        einfo[pos] = info;
    }
}

// ---------------------------------------------------------------------------
// gz device body: Z_r = tanh(ent @ W_r + rel_r) @ W_r^T. NT dwordx4 Z stores.
// ---------------------------------------------------------------------------
__device__ __forceinline__ void gz_body(
        int r, int wid, int nw, int lane,
        const ushort* __restrict__ ent_pi,
        const float*  __restrict__ W_R,
        const float*  __restrict__ rel,
        ushort* __restrict__ Z,
        float* __restrict__ myLds) {
    int m = lane & 15;
    int q = lane >> 4;

    const float* Wr = W_R + (size_t)r * DIM * DIM;
    s16x8 b1[4][2], b2[4][2];
#pragma unroll
    for (int c = 0; c < 4; ++c)
#pragma unroll
        for (int ch = 0; ch < 2; ++ch)
#pragma unroll
            for (int j = 0; j < 8; ++j) {
                b1[c][ch][j] = (short)f2bf(Wr[pcol(ch * 32 + q * 8 + j) * DIM + c * 16 + m]);
                b2[c][ch][j] = (short)f2bf(Wr[(c * 16 + m) * DIM + ch * 32 + q * 8 + j]);
            }
    float relv[4];
#pragma unroll
    for (int c = 0; c < 4; ++c) relv[c] = rel[r * DIM + c * 16 + m];

    int par = m & 1;
    const int ntiles = N_ENT / 16;

    for (int t = wid; t < ntiles; t += nw) {
        int row0 = t * 16;
        const s16x8* arow = (const s16x8*)(ent_pi + (size_t)(row0 + m) * DIM);
        s16x8 a0 = arow[q];
        s16x8 a1 = arow[4 + q];
        f32x4 acc[4];
#pragma unroll
        for (int c = 0; c < 4; ++c) acc[c] = (f32x4){0.f, 0.f, 0.f, 0.f};
#pragma unroll
        for (int c = 0; c < 4; ++c) {
            acc[c] = __builtin_amdgcn_mfma_f32_16x16x32_bf16(a0, b1[c][0], acc[c], 0, 0, 0);
            acc[c] = __builtin_amdgcn_mfma_f32_16x16x32_bf16(a1, b1[c][1], acc[c], 0, 0, 0);
        }
#pragma unroll
        for (int c = 0; c < 4; ++c)
#pragma unroll
            for (int i = 0; i < 4; ++i) {
                float x = acc[c][i] + relv[c];
                float e2 = __expf(2.f * x);
                float g = 1.f - 2.f * __builtin_amdgcn_rcpf(e2 + 1.f);
                myLds[(q * 4 + i) * 68 + c * 16 + m] = g;
            }
        union { uint u[4]; s16x8 v; } a2u[2];
#pragma unroll
        for (int ch = 0; ch < 2; ++ch) {
            const f32x4* gp = (const f32x4*)(myLds + m * 68 + ch * 32 + q * 8);
            f32x4 g0 = gp[0];
            f32x4 g1 = gp[1];
            a2u[ch].u[0] = cvt_pk_bf16(g0[0], g0[1]);
            a2u[ch].u[1] = cvt_pk_bf16(g0[2], g0[3]);
            a2u[ch].u[2] = cvt_pk_bf16(g1[0], g1[1]);
            a2u[ch].u[3] = cvt_pk_bf16(g1[2], g1[3]);
        }

        f32x4 zacc[4];
#pragma unroll
        for (int c = 0; c < 4; ++c) zacc[c] = (f32x4){0.f, 0.f, 0.f, 0.f};
#pragma unroll
        for (int c = 0; c < 4; ++c) {
            zacc[c] = __builtin_amdgcn_mfma_f32_16x16x32_bf16(a2u[0].v, b2[c][0], zacc[c], 0, 0, 0);
            zacc[c] = __builtin_amdgcn_mfma_f32_16x16x32_bf16(a2u[1].v, b2[c][1], zacc[c], 0, 0, 0);
        }

        int rowA = row0 + 4 * q + (par ? 2 : 0);
        ushort* zb = Z + ((size_t)r * N_ENT + rowA) * 64 + (m >> 1) * 8;
#pragma unroll
        for (int rep = 0; rep < 2; ++rep) {
            u32x4 Wv;
#pragma unroll
            for (int c = 0; c < 4; ++c) {
                float send = par ? zacc[c][rep] : zacc[c][2 + rep];
                float own  = par ? zacc[c][2 + rep] : zacc[c][rep];
                float oth  = __shfl_xor(send, 1, 64);
                float lo = par ? oth : own;
                float hi = par ? own : oth;
                Wv[c] = cvt_pk_bf16(lo, hi);
            }
            __builtin_nontemporal_store(Wv, (u32x4*)(zb + rep * 64));
        }
    }
}

// ---------------------------------------------------------------------------
// F1: wave-specialized fusion (round-8/11 split). Waves 0-2: gz. Wave 3:
// histogram (8 in-flight atomics/lane — maximal, each lane owns ~8 edges).
// ---------------------------------------------------------------------------
#define HIST_LANES 131072   // 2048 blocks * 64 lanes

__global__ __launch_bounds__(256, 4) void gz_hist_kernel(
        const ushort* __restrict__ ent_pi,
        const float*  __restrict__ W_R,
        const float*  __restrict__ rel,
        ushort* __restrict__ Z,
        const int* __restrict__ dst,
        int* __restrict__ counts,
        int* __restrict__ off) {
    __shared__ __align__(16) float lds[3][16 * 68 + 16];
    int lane = threadIdx.x & 63;
    int wv   = threadIdx.x >> 6;          // 0..3

    if (wv == 3) {
        int lane_gid = blockIdx.x * 64 + lane;
        int d[8]; bool v[8]; int o[8];
#pragma unroll
        for (int k = 0; k < 8; ++k) {
            int i = lane_gid + k * HIST_LANES;
            v[k] = (i < N_EDGE);
            d[k] = v[k] ? dst[i] : 0;
        }
#pragma unroll
        for (int k = 0; k < 8; ++k)
            if (v[k]) o[k] = atomicAdd(&counts[d[k]], 1);
#pragma unroll
        for (int k = 0; k < 8; ++k)
            if (v[k]) off[lane_gid + k * HIST_LANES] = o[k];
        return;
    }

    int r   = blockIdx.x >> 7;            // 128 blocks per relation
    int xb  = blockIdx.x & 127;
    int wid = xb * 3 + wv;                // [0,384)
    gz_body(r, wid, 384, lane, ent_pi, W_R, rel, Z, lds[wv]);
}

// ---------------------------------------------------------------------------
// K3b: per-edge logit = dot(ent_pi[s], Z[r][d]), edges streamed in CSR order.
// ---------------------------------------------------------------------------
__global__ __launch_bounds__(256) void att_dot_kernel(
        const ushort* __restrict__ ent_pi,
        const ushort* __restrict__ Z,
        const unsigned long long* __restrict__ einfo,
        uint2* __restrict__ es_csr,
        int n_edge) {
    int tid  = blockIdx.x * blockDim.x + threadIdx.x;
    int lane = threadIdx.x & 63;
    int sub  = lane >> 3;
    int q    = lane & 7;
    int base = (tid >> 6) * 64;
    if (base >= n_edge) return;

    int e[8];
    unsigned long long inf[8];
#pragma unroll
    for (int k = 0; k < 8; ++k) {
        e[k] = base + k * 8 + sub;
        inf[k] = (e[k] < n_edge) ? einfo[e[k]] : 0ull;
    }

    uint4 uz[8], ue[8];
#pragma unroll
    for (int k = 0; k < 8; ++k) {
        int s = (int)(inf[k] & 0xffffu);
        int d = (int)((inf[k] >> 16) & 0xffffu);
        int r = (int)((inf[k] >> 32) & 0xfu);
        uz[k] = *(const uint4*)(Z + ((size_t)r * N_ENT + d) * DIM + q * 8);
        ue[k] = *(const uint4*)(ent_pi + (size_t)s * DIM + q * 8);
    }

    float pr[8];
#pragma unroll
    for (int k = 0; k < 8; ++k) {
        float zv[8], ev[8];
        bf16x8_unpack(uz[k], zv);
        bf16x8_unpack(ue[k], ev);
        float p = 0.f;
#pragma unroll
        for (int j = 0; j < 8; ++j) p = fmaf(ev[j], zv[j], p);
        pr[k] = p;
    }
#pragma unroll
    for (int k = 0; k < 8; ++k) {
        pr[k] += __shfl_xor(pr[k], 1, 64);
        pr[k] += __shfl_xor(pr[k], 2, 64);
        pr[k] += __shfl_xor(pr[k], 4, 64);
    }

    if (q == 0) {
#pragma unroll
        for (int k = 0; k < 8; ++k)
            if (e[k] < n_edge)
                es_csr[e[k]] = make_uint2(__float_as_uint(pr[k]),
                                          (unsigned)(inf[k] & 0xffffu));
    }
}

// ---------------------------------------------------------------------------
// FUSED agg + bi-interaction MLP per node (one wave per node, grid-stride).
// Gather phase (latency-bound) then per-lane VALU MLP with LDS-cached bf16
// weights. Eliminates the N_h buffer and the 3 standalone MFMA MLP kernels;
// MLP FMA rides the gather waves' idle VALU.
//   STATS: compute softmax stats (layer 0) vs read them (layers 1,2).
//   PERM : input table/N_h in permuted column order -> pre-permute W rows.
// ---------------------------------------------------------------------------
template <int D_IN, int D_OUT, bool STATS, bool PERM>
__global__ __launch_bounds__(256) void agg_mlp_kernel(
        const ushort* __restrict__ tab,      // [N][D_IN] bf16
        const uint2* __restrict__ es_csr,
        const int* __restrict__ row_ptr,
        float2* __restrict__ stats,
        const float* __restrict__ W1, const float* __restrict__ b1,
        const float* __restrict__ W2, const float* __restrict__ b2,
        ushort* __restrict__ ho,             // [N][D_OUT] bf16 or null
        float* __restrict__ out_buf, int out_col, int n_node) {
    constexpr int LPR = D_IN / 8;            // lanes per gathered row
    constexpr int EPW = 64 / LPR;            // edges in flight per wave
    constexpr int GRP = 64 / D_OUT;          // lane groups over outputs
    constexpr int KP  = D_IN / GRP;          // k-span per group

    // W cache: interleaved pairs  w[(k>>1)*2*D_OUT + 2*j + (k&1)]
    __shared__ __align__(16) ushort w1s[D_IN * D_OUT];
    __shared__ __align__(16) ushort w2s[D_IN * D_OUT];
    __shared__ __align__(16) float rows[4][2][64];   // [wave][h|nh][dim]

    int t = threadIdx.x;
    for (int i = t; i < D_IN * D_OUT; i += 256) {
        int k = i / D_OUT, j = i % D_OUT;
        int kk = PERM ? pcol(k) : k;
        int slot = (k >> 1) * (2 * D_OUT) + 2 * j + (k & 1);
        w1s[slot] = f2bf(W1[kk * D_OUT + j]);
        w2s[slot] = f2bf(W2[kk * D_OUT + j]);
    }
    __syncthreads();

    int wv   = t >> 6;
    int lane = t & 63;
    int q    = lane % LPR;
    int sub  = lane / LPR;
    int j    = lane % D_OUT;
    int g    = lane / D_OUT;
    float bb1 = b1[j], bb2 = b2[j];
    float* hr = rows[wv][0];
    float* nr = rows[wv][1];

    for (int wid = blockIdx.x * 4 + wv; wid < n_node; wid += gridDim.x * 4) {
        int start = row_ptr[wid], end = row_ptr[wid + 1];

        float mx, inv;
        if (STATS) {
            mx = -INFINITY;
            for (int i = start + lane; i < end; i += 64)
                mx = fmaxf(mx, __uint_as_float(es_csr[i].x));
#pragma unroll
            for (int o = 32; o > 0; o >>= 1)
                mx = fmaxf(mx, __shfl_xor(mx, o, 64));
            float ssum = 0.f;
            for (int i = start + lane; i < end; i += 64)
                ssum += __expf(__uint_as_float(es_csr[i].x) - mx);
#pragma unroll
            for (int o = 32; o > 0; o >>= 1)
                ssum += __shfl_xor(ssum, o, 64);
            inv = (end > start) ? (1.0f / ssum) : 0.f;
            if (lane == 0) stats[wid] = make_float2(mx, inv);
        } else {
            float2 st = stats[wid];
            mx = st.x; inv = st.y;
        }

        // gather-accumulate
        float acc[8];
#pragma unroll
        for (int k = 0; k < 8; ++k) acc[k] = 0.f;
        for (int p = start + sub; p < end; p += EPW) {
            uint2 es = es_csr[p];
            float av = __expf(__uint_as_float(es.x) - mx);
            int   si = (int)es.y;
            uint4 u  = *(const uint4*)(tab + (size_t)si * D_IN + q * 8);
            float gg[8];
            bf16x8_unpack(u, gg);
#pragma unroll
            for (int k = 0; k < 8; ++k) acc[k] = fmaf(av, gg[k], acc[k]);
        }
#pragma unroll
        for (int mask = LPR; mask < 64; mask <<= 1)
#pragma unroll
            for (int k = 0; k < 8; ++k)
                acc[k] += __shfl_xor(acc[k], mask, 64);

        // stage N_h row (normalized) and own h row into LDS
        if (lane < LPR) {
#pragma unroll
            for (int k = 0; k < 8; ++k) nr[lane * 8 + k] = acc[k] * inv;
            uint4 hu = *(const uint4*)(tab + (size_t)wid * D_IN + lane * 8);
            float hv[8];
            bf16x8_unpack(hu, hv);
#pragma unroll
            for (int k = 0; k < 8; ++k) hr[lane * 8 + k] = hv[k];
        }
        asm volatile("s_waitcnt lgkmcnt(0)" ::: "memory");

        // per-lane MLP: output dim j, k-range per group
        float o1 = 0.f, o2 = 0.f;
#pragma unroll
        for (int k = g * KP; k < g * KP + KP; k += 2) {
            float2 hv = *(float2*)&hr[k];
            float2 nv = *(float2*)&nr[k];
            uint w1p = *(uint*)&w1s[(k >> 1) * (2 * D_OUT) + 2 * j];
            uint w2p = *(uint*)&w2s[(k >> 1) * (2 * D_OUT) + 2 * j];
            float w1a = __uint_as_float((w1p & 0xffffu) << 16);
            float w1b = __uint_as_float(w1p & 0xffff0000u);
            float w2a = __uint_as_float((w2p & 0xffffu) << 16);
            float w2b = __uint_as_float(w2p & 0xffff0000u);
            o1 = fmaf(hv.x + nv.x, w1a, o1);
            o1 = fmaf(hv.y + nv.y, w1b, o1);
            o2 = fmaf(hv.x * nv.x, w2a, o2);
            o2 = fmaf(hv.y * nv.y, w2b, o2);
        }
#pragma unroll
        for (int mask = D_OUT; mask < 64; mask <<= 1) {
            o1 += __shfl_xor(o1, mask, 64);
            o2 += __shfl_xor(o2, mask, 64);
        }
        o1 += bb1; o2 += bb2;
        float r1 = (o1 >= 0.f) ? o1 : 0.01f * o1;
        float r2 = (o2 >= 0.f) ? o2 : 0.01f * o2;
        float rr = r1 + r2;
        float part = (g == 0) ? rr * rr : 0.f;
#pragma unroll
        for (int mask = 1; mask < 64; mask <<= 1)
            part += __shfl_xor(part, mask, 64);
        float invn = 1.f / fmaxf(sqrtf(part), 1e-12f);
        if (g == 0) {
            out_buf[(size_t)wid * OUT_STRIDE + out_col + j] = rr * invn;
            if (ho) ho[(size_t)wid * D_OUT + j] = f2bf(rr);
        }
    }
}

// ---------------------------------------------------------------------------
extern "C" void kernel_launch(void* const* d_in, const int* in_sizes, int n_in,
                              void* d_out, int out_size, void* d_ws, size_t ws_size,
                              hipStream_t stream) {
    const float* ent  = (const float*)d_in[0];
    const float* rel  = (const float*)d_in[1];
    const float* W_R  = (const float*)d_in[2];
    const float* W1_0 = (const float*)d_in[3];
    const float* b1_0 = (const float*)d_in[4];
    const float* W2_0 = (const float*)d_in[5];
    const float* b2_0 = (const float*)d_in[6];
    const float* W1_1 = (const float*)d_in[7];
    const float* b1_1 = (const float*)d_in[8];
    const float* W2_1 = (const float*)d_in[9];
    const float* b2_1 = (const float*)d_in[10];
    const float* W1_2 = (const float*)d_in[11];
    const float* b1_2 = (const float*)d_in[12];
    const float* W2_2 = (const float*)d_in[13];
    const float* b2_2 = (const float*)d_in[14];
    const int*   src   = (const int*)d_in[15];
    const int*   dst   = (const int*)d_in[16];
    const int*   etype = (const int*)d_in[17];
    float* out = (float*)d_out;

    // workspace layout
    char* w = (char*)d_ws;
    uint2*  es_csr  = (uint2*)w;  w += (size_t)N_EDGE * 8;              // 8 MB packed
    unsigned long long* einfo = (unsigned long long*)w;
    w += (size_t)N_EDGE * 8;                                            // 8 MB CSR-order edge info
    int*    counts  = (int*)w;    w += (size_t)(N_ENT + 64) * 4;
    int*    row_ptr = (int*)w;    w += (size_t)(N_ENT + 64) * 4;
    float2* stats   = (float2*)w; w += (size_t)(N_ENT + 64) * 8;
    int*    excl    = (int*)w;    w += (size_t)(N_ENT + 64) * 4;
    int*    bsum    = (int*)w;    w += 256 * 4;
    int*    boff    = (int*)w;    w += 256 * 4;
    ushort* ent_pi  = (ushort*)w; w += (size_t)N_ENT * 64 * 2;          // 6.4 MB
    ushort* h1      = (ushort*)w; w += (size_t)N_ENT * 64 * 2;          // 6.4 MB
    ushort* h2      = (ushort*)w; w += (size_t)N_ENT * 32 * 2;          // 3.2 MB
    ushort* Z       = (ushort*)w;                                       // 102 MB
    (void)ws_size;

    // overlay: off lives in the es_csr region (written by gz_hist, read by
    // scan3_pos, dead before att_dot writes es_csr).
    int* off = (int*)es_csr;

    hipMemsetAsync(counts, 0, (size_t)N_ENT * 4, stream);

    const int nb = (N_ENT + 255) / 256;

    prep_convert_kernel<<<(N_ENT * DIM + 255) / 256, 256, 0, stream>>>(
        ent, ent_pi, out);

    gz_hist_kernel<<<2048, 256, 0, stream>>>(
        ent_pi, W_R, rel, Z, dst, counts, off);

    scan1_kernel<<<nb, 256, 0, stream>>>(counts, excl, bsum, N_ENT);
    scan2_kernel<<<1, 256, 0, stream>>>(bsum, boff, row_ptr, nb, N_ENT);
    scan3_pos_kernel<<<(N_EDGE + 255) / 256, 256, 0, stream>>>(
        excl, boff, row_ptr, src, dst, etype, off, einfo);

    att_dot_kernel<<<((N_EDGE + 63) / 64 * 64 + 255) / 256, 256, 0, stream>>>(
        ent_pi, Z, einfo, es_csr, N_EDGE);

    // ---- fused agg+MLP layers ----
    agg_mlp_kernel<64, 64, true,  true ><<<4096, 256, 0, stream>>>(
        ent_pi, es_csr, row_ptr, stats, W1_0, b1_0, W2_0, b2_0, h1, out, 64, N_ENT);
    agg_mlp_kernel<64, 32, false, false><<<4096, 256, 0, stream>>>(
        h1, es_csr, row_ptr, stats, W1_1, b1_1, W2_1, b2_1, h2, out, 128, N_ENT);
    agg_mlp_kernel<32, 16, false, false><<<4096, 256, 0, stream>>>(
        h2, es_csr, row_ptr, stats, W1_2, b1_2, W2_2, b2_2, nullptr, out, 160, N_ENT);
}

// Round 13
// 364.291 us; speedup vs baseline: 1.1443x; 1.1443x over previous
//
#include <hip/hip_runtime.h>
#include <hip/hip_bf16.h>
#include <cmath>

#define N_ENT  50000
#define N_RELS 16
#define N_EDGE 1000000
#define DIM    64
#define OUT_STRIDE 176

typedef float f32x4 __attribute__((ext_vector_type(4)));
typedef short s16x8 __attribute__((ext_vector_type(8)));
typedef uint  u32x4 __attribute__((ext_vector_type(4)));

__device__ inline void bf16x8_unpack(uint4 u, float* f) {
    f[0] = __uint_as_float((u.x & 0xffffu) << 16);
    f[1] = __uint_as_float(u.x & 0xffff0000u);
    f[2] = __uint_as_float((u.y & 0xffffu) << 16);
    f[3] = __uint_as_float(u.y & 0xffff0000u);
    f[4] = __uint_as_float((u.z & 0xffffu) << 16);
    f[5] = __uint_as_float(u.z & 0xffff0000u);
    f[6] = __uint_as_float((u.w & 0xffffu) << 16);
    f[7] = __uint_as_float(u.w & 0xffff0000u);
}

__device__ inline ushort f2bf(float x) {
    __hip_bfloat16 b = __float2bfloat16(x);
    return *(ushort*)&b;
}

__device__ inline uint cvt_pk_bf16(float lo, float hi) {
    uint r;
    asm("v_cvt_pk_bf16_f32 %0, %1, %2" : "=v"(r) : "v"(lo), "v"(hi));
    return r;
}

// Column permutation for the packed-P / ent_pi layout.
__device__ __host__ inline int pcol(int p) {
    int qp = (p >> 3) & 7;
    int k  = p & 7;
    return 16 * (k >> 1) + 2 * qp + (k & 1);
}

// ---------------------------------------------------------------------------
// K0a: streaming prep — ent fp32 -> permuted bf16 table + out[:,0:64] copy,
// plus permuted bf16 rel table (16x64, for att_dot's in-flight tanh).
// ---------------------------------------------------------------------------
__global__ __launch_bounds__(256) void prep_convert_kernel(
        const float* __restrict__ ent,
        const float* __restrict__ rel,
        ushort* __restrict__ ent_pi,
        ushort* __restrict__ rel_pi,
        float* __restrict__ out) {
    int i = blockIdx.x * blockDim.x + threadIdx.x;
    if (i < N_ENT * DIM) {
        float v = ent[i];
        ushort b = f2bf(v);
        int n = i >> 6, c = i & 63;
        int pos = ((c & 15) >> 1) * 8 + ((c >> 4) << 1) + (c & 1);
        ent_pi[(size_t)n * 64 + pos] = b;
        out[(size_t)n * OUT_STRIDE + c] = v;
    }
    if (i < N_RELS * DIM) {
        int r = i >> 6, c = i & 63;
        int pos = ((c & 15) >> 1) * 8 + ((c >> 4) << 1) + (c & 1);
        rel_pi[r * 64 + pos] = f2bf(rel[i]);
    }
}

// ---------------------------------------------------------------------------
// K2: 3-phase multi-block exclusive scan counts -> row_ptr
// ---------------------------------------------------------------------------
__global__ __launch_bounds__(256) void scan1_kernel(
        const int* __restrict__ counts, int* __restrict__ excl,
        int* __restrict__ bsum, int n) {
    __shared__ int sh[256];
    int t = threadIdx.x;
    int i = blockIdx.x * 256 + t;
    int c = (i < n) ? counts[i] : 0;
    sh[t] = c;
    __syncthreads();
    for (int off = 1; off < 256; off <<= 1) {
        int v = (t >= off) ? sh[t - off] : 0;
        __syncthreads();
        sh[t] += v;
        __syncthreads();
    }
    if (i < n) excl[i] = sh[t] - c;
    if (t == 255) bsum[blockIdx.x] = sh[255];
}

__global__ __launch_bounds__(256) void scan2_kernel(
        const int* __restrict__ bsum, int* __restrict__ boff,
        int* __restrict__ row_ptr, int nb, int n) {
    __shared__ int sh[256];
    int t = threadIdx.x;
    int v = (t < nb) ? bsum[t] : 0;
    sh[t] = v;
    __syncthreads();
    for (int off = 1; off < 256; off <<= 1) {
        int x = (t >= off) ? sh[t - off] : 0;
        __syncthreads();
        sh[t] += x;
        __syncthreads();
    }
    if (t < nb) boff[t] = sh[t] - v;
    if (t == nb - 1) row_ptr[n] = sh[t];
}

// K3: finalize row_ptr AND scatter per-edge info into CSR ORDER:
//   einfo[pos] = src(16b) | dst(16b)<<16 | rel(4b)<<32
__global__ __launch_bounds__(256) void scan3_pos_kernel(
        const int* __restrict__ excl, const int* __restrict__ boff,
        int* __restrict__ row_ptr,
        const int* __restrict__ src, const int* __restrict__ dst,
        const int* __restrict__ etype, const int* __restrict__ off,
        unsigned long long* __restrict__ einfo) {
    int i = blockIdx.x * blockDim.x + threadIdx.x;
    if (i < N_ENT) row_ptr[i] = excl[i] + boff[i >> 8];
    if (i < N_EDGE) {
        int d = dst[i];
        int pos = excl[d] + boff[d >> 8] + off[i];
        unsigned long long info =
              (unsigned long long)(unsigned)src[i]
            | ((unsigned long long)(unsigned)d << 16)
            | ((unsigned long long)(unsigned)etype[i] << 32);
        einfo[pos] = info;
    }
}

// ---------------------------------------------------------------------------
// P body: P_r = ent @ W_r  (ONE gemm — tanh/rel moved into att_dot; the
// reference att is sum_e P[s]*tanh(P[d]+rel), so the 2nd gemm of the old
// Z-form is unnecessary). Packed permuted bf16 rows, NT dwordx4 stores.
// ---------------------------------------------------------------------------
__device__ __forceinline__ void p_body(
        int r, int wid, int nw, int lane,
        const ushort* __restrict__ ent_pi,
        const float*  __restrict__ W_R,
        ushort* __restrict__ P) {
    int m = lane & 15;
    int q = lane >> 4;

    const float* Wr = W_R + (size_t)r * DIM * DIM;
    s16x8 b1[4][2];
#pragma unroll
    for (int c = 0; c < 4; ++c)
#pragma unroll
        for (int ch = 0; ch < 2; ++ch)
#pragma unroll
            for (int j = 0; j < 8; ++j)
                b1[c][ch][j] = (short)f2bf(Wr[pcol(ch * 32 + q * 8 + j) * DIM + c * 16 + m]);

    int par = m & 1;
    const int ntiles = N_ENT / 16;

    for (int t = wid; t < ntiles; t += nw) {
        int row0 = t * 16;
        const s16x8* arow = (const s16x8*)(ent_pi + (size_t)(row0 + m) * DIM);
        s16x8 a0 = arow[q];
        s16x8 a1 = arow[4 + q];
        f32x4 acc[4];
#pragma unroll
        for (int c = 0; c < 4; ++c) acc[c] = (f32x4){0.f, 0.f, 0.f, 0.f};
#pragma unroll
        for (int c = 0; c < 4; ++c) {
            acc[c] = __builtin_amdgcn_mfma_f32_16x16x32_bf16(a0, b1[c][0], acc[c], 0, 0, 0);
            acc[c] = __builtin_amdgcn_mfma_f32_16x16x32_bf16(a1, b1[c][1], acc[c], 0, 0, 0);
        }

        // packed store: lane holds P[row0+4q+i][c*16+m] (true cols) -> permuted
        int rowA = row0 + 4 * q + (par ? 2 : 0);
        ushort* pb = P + ((size_t)r * N_ENT + rowA) * 64 + (m >> 1) * 8;
#pragma unroll
        for (int rep = 0; rep < 2; ++rep) {
            u32x4 Wv;
#pragma unroll
            for (int c = 0; c < 4; ++c) {
                float send = par ? acc[c][rep] : acc[c][2 + rep];
                float own  = par ? acc[c][2 + rep] : acc[c][rep];
                float oth  = __shfl_xor(send, 1, 64);
                float lo = par ? oth : own;
                float hi = par ? own : oth;
                Wv[c] = cvt_pk_bf16(lo, hi);
            }
            __builtin_nontemporal_store(Wv, (u32x4*)(pb + rep * 64));
        }
    }
}

// ---------------------------------------------------------------------------
// F1: wave-specialized fusion (round-8/11 split). Waves 0-2: P gemm.
// Wave 3: histogram, 8 in-flight atomics/lane (maximal concurrency).
// ---------------------------------------------------------------------------
#define HIST_LANES 131072   // 2048 blocks * 64 lanes

__global__ __launch_bounds__(256, 4) void gz_hist_kernel(
        const ushort* __restrict__ ent_pi,
        const float*  __restrict__ W_R,
        ushort* __restrict__ P,
        const int* __restrict__ dst,
        int* __restrict__ counts,
        int* __restrict__ off) {
    int lane = threadIdx.x & 63;
    int wv   = threadIdx.x >> 6;          // 0..3

    if (wv == 3) {
        int lane_gid = blockIdx.x * 64 + lane;
        int d[8]; bool v[8]; int o[8];
#pragma unroll
        for (int k = 0; k < 8; ++k) {
            int i = lane_gid + k * HIST_LANES;
            v[k] = (i < N_EDGE);
            d[k] = v[k] ? dst[i] : 0;
        }
#pragma unroll
        for (int k = 0; k < 8; ++k)
            if (v[k]) o[k] = atomicAdd(&counts[d[k]], 1);
#pragma unroll
        for (int k = 0; k < 8; ++k)
            if (v[k]) off[lane_gid + k * HIST_LANES] = o[k];
        return;
    }

    int r   = blockIdx.x >> 7;            // 128 blocks per relation
    int xb  = blockIdx.x & 127;
    int wid = xb * 3 + wv;                // [0,384)
    p_body(r, wid, 384, lane, ent_pi, W_R, P);
}

// ---------------------------------------------------------------------------
// K3b: per-edge logit = sum_c P[r][s][c] * tanh(P[r][d][c] + rel[r][c]),
// edges streamed in CSR order. 64 edges/wave, 16 gathers in flight.
// tanh trans-ops hide under gather latency (VALUBusy was ~15%).
// ---------------------------------------------------------------------------
__global__ __launch_bounds__(256) void att_dot_kernel(
        const ushort* __restrict__ P,
        const ushort* __restrict__ rel_pi,
        const unsigned long long* __restrict__ einfo,
        uint2* __restrict__ es_csr,
        int n_edge) {
    int tid  = blockIdx.x * blockDim.x + threadIdx.x;
    int lane = threadIdx.x & 63;
    int sub  = lane >> 3;
    int q    = lane & 7;
    int base = (tid >> 6) * 64;
    if (base >= n_edge) return;

    int e[8];
    unsigned long long inf[8];
#pragma unroll
    for (int k = 0; k < 8; ++k) {
        e[k] = base + k * 8 + sub;
        inf[k] = (e[k] < n_edge) ? einfo[e[k]] : 0ull;
    }

    uint4 uz[8], ue[8];
#pragma unroll
    for (int k = 0; k < 8; ++k) {
        int s = (int)(inf[k] & 0xffffu);
        int d = (int)((inf[k] >> 16) & 0xffffu);
        int r = (int)((inf[k] >> 32) & 0xfu);
        uz[k] = *(const uint4*)(P + ((size_t)r * N_ENT + d) * DIM + q * 8);
        ue[k] = *(const uint4*)(P + ((size_t)r * N_ENT + s) * DIM + q * 8);
    }

    float pr[8];
#pragma unroll
    for (int k = 0; k < 8; ++k) {
        int r = (int)((inf[k] >> 32) & 0xfu);
        uint4 ur = *(const uint4*)(rel_pi + r * 64 + q * 8);
        float zv[8], ev[8], rl[8];
        bf16x8_unpack(uz[k], zv);
        bf16x8_unpack(ue[k], ev);
        bf16x8_unpack(ur, rl);
        float p = 0.f;
#pragma unroll
        for (int j = 0; j < 8; ++j) {
            float x = zv[j] + rl[j];
            float g = 1.f - 2.f * __builtin_amdgcn_rcpf(__expf(2.f * x) + 1.f);
            p = fmaf(ev[j], g, p);
        }
        pr[k] = p;
    }
#pragma unroll
    for (int k = 0; k < 8; ++k) {
        pr[k] += __shfl_xor(pr[k], 1, 64);
        pr[k] += __shfl_xor(pr[k], 2, 64);
        pr[k] += __shfl_xor(pr[k], 4, 64);
    }

    if (q == 0) {
#pragma unroll
        for (int k = 0; k < 8; ++k)
            if (e[k] < n_edge)
                es_csr[e[k]] = make_uint2(__float_as_uint(pr[k]),
                                          (unsigned)(inf[k] & 0xffffu));
    }
}

// ---------------------------------------------------------------------------
// K6a-0: layer-0 aggregation with fused softmax stats. WRITES BACK the
// normalized weight a_e into es_csr.x so layers 1/2 skip stats+exp.
// ---------------------------------------------------------------------------
__global__ __launch_bounds__(256) void agg64s_kernel(
        const ushort* __restrict__ tab,      // [N][64] bf16
        uint2* __restrict__ es_csr,
        const int* __restrict__ row_ptr,
        float* __restrict__ N_h, int n_node) {
    int wid  = (blockIdx.x * blockDim.x + threadIdx.x) >> 6;
    int lane = threadIdx.x & 63;
    if (wid >= n_node) return;
    int q   = lane & 7;
    int sub = lane >> 3;

    int start = row_ptr[wid], end = row_ptr[wid + 1];

    // stats
    float mx = -INFINITY;
    for (int i = start + lane; i < end; i += 64)
        mx = fmaxf(mx, __uint_as_float(es_csr[i].x));
#pragma unroll
    for (int o = 32; o > 0; o >>= 1)
        mx = fmaxf(mx, __shfl_xor(mx, o, 64));
    float ssum = 0.f;
    for (int i = start + lane; i < end; i += 64)
        ssum += __expf(__uint_as_float(es_csr[i].x) - mx);
#pragma unroll
    for (int o = 32; o > 0; o >>= 1)
        ssum += __shfl_xor(ssum, o, 64);
    float inv = (end > start) ? (1.0f / ssum) : 0.f;

    // weighted gather + normalized-weight write-back
    float acc[8];
#pragma unroll
    for (int j = 0; j < 8; ++j) acc[j] = 0.f;

    for (int p = start + sub; p < end; p += 8) {
        uint2 es = es_csr[p];
        float av = __expf(__uint_as_float(es.x) - mx) * inv;
        int   si = (int)es.y;
        if (q == 0) es_csr[p].x = __float_as_uint(av);
        uint4 u  = *(const uint4*)(tab + (size_t)si * 64 + q * 8);
        float g[8];
        bf16x8_unpack(u, g);
#pragma unroll
        for (int j = 0; j < 8; ++j) acc[j] = fmaf(av, g[j], acc[j]);
    }
#pragma unroll
    for (int mask = 8; mask < 64; mask <<= 1)
#pragma unroll
        for (int j = 0; j < 8; ++j)
            acc[j] += __shfl_xor(acc[j], mask, 64);

    if (sub == 0) {
        float* dstp = N_h + (size_t)wid * 64 + q * 8;
        *(float4*)(dstp)     = (float4){acc[0], acc[1], acc[2], acc[3]};
        *(float4*)(dstp + 4) = (float4){acc[4], acc[5], acc[6], acc[7]};
    }
}

// ---------------------------------------------------------------------------
// K6a: 64-wide aggregation, pre-normalized weights (layer 1).
// ---------------------------------------------------------------------------
__global__ __launch_bounds__(256) void agg64_kernel(
        const ushort* __restrict__ tab,      // [N][64] bf16
        const uint2* __restrict__ es_csr,
        const int* __restrict__ row_ptr,
        float* __restrict__ N_h, int n_node) {
    int wid  = (blockIdx.x * blockDim.x + threadIdx.x) >> 6;
    int lane = threadIdx.x & 63;
    if (wid >= n_node) return;
    int q   = lane & 7;
    int sub = lane >> 3;

    int start = row_ptr[wid], end = row_ptr[wid + 1];
    float acc[8];
#pragma unroll
    for (int j = 0; j < 8; ++j) acc[j] = 0.f;

    for (int p = start + sub; p < end; p += 8) {
        uint2 es = es_csr[p];
        float av = __uint_as_float(es.x);
        int   si = (int)es.y;
        uint4 u  = *(const uint4*)(tab + (size_t)si * 64 + q * 8);
        float g[8];
        bf16x8_unpack(u, g);
#pragma unroll
        for (int j = 0; j < 8; ++j) acc[j] = fmaf(av, g[j], acc[j]);
    }
#pragma unroll
    for (int mask = 8; mask < 64; mask <<= 1)
#pragma unroll
        for (int j = 0; j < 8; ++j)
            acc[j] += __shfl_xor(acc[j], mask, 64);

    if (sub == 0) {
        float* dstp = N_h + (size_t)wid * 64 + q * 8;
        *(float4*)(dstp)     = (float4){acc[0], acc[1], acc[2], acc[3]};
        *(float4*)(dstp + 4) = (float4){acc[4], acc[5], acc[6], acc[7]};
    }
}

// K6a': 32-wide aggregation, pre-normalized weights (layer 2).
__global__ __launch_bounds__(256) void agg32_kernel(
        const ushort* __restrict__ tab,      // [N][32] bf16
        const uint2* __restrict__ es_csr,
        const int* __restrict__ row_ptr,
        float* __restrict__ N_h, int n_node) {
    int wid  = (blockIdx.x * blockDim.x + threadIdx.x) >> 6;
    int lane = threadIdx.x & 63;
    if (wid >= n_node) return;
    int q   = lane & 3;
    int sub = lane >> 2;

    int start = row_ptr[wid], end = row_ptr[wid + 1];
    float acc[8];
#pragma unroll
    for (int j = 0; j < 8; ++j) acc[j] = 0.f;

    for (int p = start + sub; p < end; p += 16) {
        uint2 es = es_csr[p];
        float av = __uint_as_float(es.x);
        int   si = (int)es.y;
        uint4 u  = *(const uint4*)(tab + (size_t)si * 32 + q * 8);
        float g[8];
        bf16x8_unpack(u, g);
#pragma unroll
        for (int j = 0; j < 8; ++j) acc[j] = fmaf(av, g[j], acc[j]);
    }
#pragma unroll
    for (int mask = 4; mask < 64; mask <<= 1)
#pragma unroll
        for (int j = 0; j < 8; ++j)
            acc[j] += __shfl_xor(acc[j], mask, 64);

    if (sub == 0) {
        float* dstp = N_h + (size_t)wid * 32 + q * 8;
        *(float4*)(dstp)     = (float4){acc[0], acc[1], acc[2], acc[3]};
        *(float4*)(dstp + 4) = (float4){acc[4], acc[5], acc[6], acc[7]};
    }
}

// ---------------------------------------------------------------------------
// K6b: dense bi-interaction MLP via MFMA, fused bias/leaky/l2-norm epilogue.
// ---------------------------------------------------------------------------
template <int D_IN, int D_OUT, bool PERM>
__global__ __launch_bounds__(256) void mlp_mfma_kernel(
        const ushort* __restrict__ h,        // [N][D_IN] bf16
        const float* __restrict__ N_h,       // [N][D_IN] f32
        const float* __restrict__ W1, const float* __restrict__ b1,
        const float* __restrict__ W2, const float* __restrict__ b2,
        ushort* __restrict__ ho,             // [N][D_OUT] bf16 (or null)
        float* __restrict__ out_buf, int out_col) {
    constexpr int CH = D_IN / 32;
    constexpr int CT = D_OUT / 16;

    int lane = threadIdx.x & 63;
    int m    = lane & 15;
    int q    = lane >> 4;
    int wid  = blockIdx.x * (blockDim.x >> 6) + (threadIdx.x >> 6);
    int nw   = gridDim.x * (blockDim.x >> 6);

    s16x8 bu[CT][CH], bv[CT][CH];
#pragma unroll
    for (int c = 0; c < CT; ++c)
#pragma unroll
        for (int ch = 0; ch < CH; ++ch)
#pragma unroll
            for (int j = 0; j < 8; ++j) {
                int p = ch * 32 + q * 8 + j;
                int k = PERM ? pcol(p) : p;
                bu[c][ch][j] = (short)f2bf(W1[k * D_OUT + c * 16 + m]);
                bv[c][ch][j] = (short)f2bf(W2[k * D_OUT + c * 16 + m]);
            }

    const int ntiles = N_ENT / 16;
    for (int t = wid; t < ntiles; t += nw) {
        int row0 = t * 16;
        s16x8 au[CH], av[CH];
#pragma unroll
        for (int ch = 0; ch < CH; ++ch) {
            uint4 hu = *(const uint4*)(h + (size_t)(row0 + m) * D_IN + ch * 32 + q * 8);
            float hv8[8];
            bf16x8_unpack(hu, hv8);
            const float4* np = (const float4*)(N_h + (size_t)(row0 + m) * D_IN + ch * 32 + q * 8);
            float4 na = np[0], nb = np[1];
            float nv[8] = {na.x, na.y, na.z, na.w, nb.x, nb.y, nb.z, nb.w};
#pragma unroll
            for (int j = 0; j < 8; ++j) {
                au[ch][j] = (short)f2bf(hv8[j] + nv[j]);
                av[ch][j] = (short)f2bf(hv8[j] * nv[j]);
            }
        }

        f32x4 accu[CT], accv[CT];
#pragma unroll
        for (int c = 0; c < CT; ++c) {
            accu[c] = (f32x4){0.f, 0.f, 0.f, 0.f};
            accv[c] = (f32x4){0.f, 0.f, 0.f, 0.f};
        }
#pragma unroll
        for (int c = 0; c < CT; ++c)
#pragma unroll
            for (int ch = 0; ch < CH; ++ch) {
                accu[c] = __builtin_amdgcn_mfma_f32_16x16x32_bf16(au[ch], bu[c][ch], accu[c], 0, 0, 0);
                accv[c] = __builtin_amdgcn_mfma_f32_16x16x32_bf16(av[ch], bv[c][ch], accv[c], 0, 0, 0);
            }

        float res[CT][4];
        float sq[4] = {0.f, 0.f, 0.f, 0.f};
#pragma unroll
        for (int c = 0; c < CT; ++c) {
            float bb1 = b1[c * 16 + m];
            float bb2 = b2[c * 16 + m];
#pragma unroll
            for (int i = 0; i < 4; ++i) {
                float o1 = accu[c][i] + bb1;
                float o2 = accv[c][i] + bb2;
                float r1 = (o1 >= 0.f) ? o1 : 0.01f * o1;
                float r2 = (o2 >= 0.f) ? o2 : 0.01f * o2;
                float rr = r1 + r2;
                res[c][i] = rr;
                sq[i] = fmaf(rr, rr, sq[i]);
            }
        }
#pragma unroll
        for (int mask = 1; mask < 16; mask <<= 1)
#pragma unroll
            for (int i = 0; i < 4; ++i)
                sq[i] += __shfl_xor(sq[i], mask, 64);

#pragma unroll
        for (int i = 0; i < 4; ++i) {
            int row = row0 + q * 4 + i;
            float inv = 1.f / fmaxf(sqrtf(sq[i]), 1e-12f);
#pragma unroll
            for (int c = 0; c < CT; ++c) {
                int col = c * 16 + m;
                out_buf[(size_t)row * OUT_STRIDE + out_col + col] = res[c][i] * inv;
                if (ho) ho[(size_t)row * D_OUT + col] = f2bf(res[c][i]);
            }
        }
    }
}

// ---------------------------------------------------------------------------
extern "C" void kernel_launch(void* const* d_in, const int* in_sizes, int n_in,
                              void* d_out, int out_size, void* d_ws, size_t ws_size,
                              hipStream_t stream) {
    const float* ent  = (const float*)d_in[0];
    const float* rel  = (const float*)d_in[1];
    const float* W_R  = (const float*)d_in[2];
    const float* W1_0 = (const float*)d_in[3];
    const float* b1_0 = (const float*)d_in[4];
    const float* W2_0 = (const float*)d_in[5];
    const float* b2_0 = (const float*)d_in[6];
    const float* W1_1 = (const float*)d_in[7];
    const float* b1_1 = (const float*)d_in[8];
    const float* W2_1 = (const float*)d_in[9];
    const float* b2_1 = (const float*)d_in[10];
    const float* W1_2 = (const float*)d_in[11];
    const float* b1_2 = (const float*)d_in[12];
    const float* W2_2 = (const float*)d_in[13];
    const float* b2_2 = (const float*)d_in[14];
    const int*   src   = (const int*)d_in[15];
    const int*   dst   = (const int*)d_in[16];
    const int*   etype = (const int*)d_in[17];
    float* out = (float*)d_out;

    // workspace layout
    char* w = (char*)d_ws;
    uint2*  es_csr  = (uint2*)w;  w += (size_t)N_EDGE * 8;              // 8 MB packed
    int*    counts  = (int*)w;    w += (size_t)(N_ENT + 64) * 4;
    int*    row_ptr = (int*)w;    w += (size_t)(N_ENT + 64) * 4;
    int*    excl    = (int*)w;    w += (size_t)(N_ENT + 64) * 4;
    int*    bsum    = (int*)w;    w += 256 * 4;
    int*    boff    = (int*)w;    w += 256 * 4;
    ushort* rel_pi  = (ushort*)w; w += (size_t)N_RELS * 64 * 2;         // 2 KB
    ushort* ent_pi  = (ushort*)w; w += (size_t)N_ENT * 64 * 2;          // 6.4 MB
    ushort* h1      = (ushort*)w; w += (size_t)N_ENT * 64 * 2;          // 6.4 MB
    ushort* h2      = (ushort*)w; w += (size_t)N_ENT * 32 * 2;          // 3.2 MB
    float*  N_h     = (float*)w;  w += (size_t)N_ENT * 64 * 4;          // 12.8 MB
    ushort* P       = (ushort*)w;                                       // 102 MB
    (void)ws_size;

    // stream-ordered overlays:
    //  - off lives in the es_csr region: written by gz_hist, read by
    //    scan3_pos, dead before att_dot writes es_csr.
    //  - einfo lives in the N_h region: written by scan3_pos, read by
    //    att_dot, dead before agg writes N_h.
    int* off = (int*)es_csr;
    unsigned long long* einfo = (unsigned long long*)N_h;

    (void)hipMemsetAsync(counts, 0, (size_t)N_ENT * 4, stream);

    const int nb = (N_ENT + 255) / 256;

    prep_convert_kernel<<<(N_ENT * DIM + 255) / 256, 256, 0, stream>>>(
        ent, rel, ent_pi, rel_pi, out);

    // F1: P gemm (waves 0-2) || edge histogram (wave 3).
    gz_hist_kernel<<<2048, 256, 0, stream>>>(
        ent_pi, W_R, P, dst, counts, off);

    scan1_kernel<<<nb, 256, 0, stream>>>(counts, excl, bsum, N_ENT);
    scan2_kernel<<<1, 256, 0, stream>>>(bsum, boff, row_ptr, nb, N_ENT);
    scan3_pos_kernel<<<(N_EDGE + 255) / 256, 256, 0, stream>>>(
        excl, boff, row_ptr, src, dst, etype, off, einfo);

    att_dot_kernel<<<((N_EDGE + 63) / 64 * 64 + 255) / 256, 256, 0, stream>>>(
        P, rel_pi, einfo, es_csr, N_EDGE);

    const int aggGrid = (N_ENT + 3) / 4;
    const int mlpGrid = 782;

    // ---- layer 0: agg with fused stats + a_e write-back ----
    agg64s_kernel<<<aggGrid, 256, 0, stream>>>(ent_pi, es_csr, row_ptr, N_h, N_ENT);
    mlp_mfma_kernel<64, 64, true><<<mlpGrid, 256, 0, stream>>>(
        ent_pi, N_h, W1_0, b1_0, W2_0, b2_0, h1, out, 64);

    // ---- layer 1: D_IN=64 (h1) -> D_OUT=32 (h2) ----
    agg64_kernel<<<aggGrid, 256, 0, stream>>>(h1, es_csr, row_ptr, N_h, N_ENT);
    mlp_mfma_kernel<64, 32, false><<<mlpGrid, 256, 0, stream>>>(
        h1, N_h, W1_1, b1_1, W2_1, b2_1, h2, out, 128);

    // ---- layer 2: D_IN=32 (h2) -> D_OUT=16 ----
    agg32_kernel<<<aggGrid, 256, 0, stream>>>(h2, es_csr, row_ptr, N_h, N_ENT);
    mlp_mfma_kernel<32, 16, false><<<mlpGrid, 256, 0, stream>>>(
        h2, N_h, W1_2, b1_2, W2_2, b2_2, nullptr, out, 160);
}

// Round 14
// 363.026 us; speedup vs baseline: 1.1483x; 1.0035x over previous
//
#include <hip/hip_runtime.h>
#include <hip/hip_bf16.h>
#include <cmath>

#define N_ENT  50000
#define N_RELS 16
#define N_EDGE 1000000
#define DIM    64
#define OUT_STRIDE 176

typedef float f32x4 __attribute__((ext_vector_type(4)));
typedef short s16x8 __attribute__((ext_vector_type(8)));
typedef uint  u32x4 __attribute__((ext_vector_type(4)));

__device__ inline void bf16x8_unpack(uint4 u, float* f) {
    f[0] = __uint_as_float((u.x & 0xffffu) << 16);
    f[1] = __uint_as_float(u.x & 0xffff0000u);
    f[2] = __uint_as_float((u.y & 0xffffu) << 16);
    f[3] = __uint_as_float(u.y & 0xffff0000u);
    f[4] = __uint_as_float((u.z & 0xffffu) << 16);
    f[5] = __uint_as_float(u.z & 0xffff0000u);
    f[6] = __uint_as_float((u.w & 0xffffu) << 16);
    f[7] = __uint_as_float(u.w & 0xffff0000u);
}

__device__ inline ushort f2bf(float x) {
    __hip_bfloat16 b = __float2bfloat16(x);
    return *(ushort*)&b;
}

__device__ inline uint cvt_pk_bf16(float lo, float hi) {
    uint r;
    asm("v_cvt_pk_bf16_f32 %0, %1, %2" : "=v"(r) : "v"(lo), "v"(hi));
    return r;
}

// Column permutation for the packed-Z / ent_pi layout.
__device__ __host__ inline int pcol(int p) {
    int qp = (p >> 3) & 7;
    int k  = p & 7;
    return 16 * (k >> 1) + 2 * qp + (k & 1);
}

// ---------------------------------------------------------------------------
// K0a: streaming prep only — ent fp32 -> permuted bf16 table + out[:,0:64].
// ---------------------------------------------------------------------------
__global__ __launch_bounds__(256) void prep_convert_kernel(
        const float* __restrict__ ent,
        ushort* __restrict__ ent_pi,
        float* __restrict__ out) {
    int i = blockIdx.x * blockDim.x + threadIdx.x;
    if (i < N_ENT * DIM) {
        float v = ent[i];
        ushort b = f2bf(v);
        int n = i >> 6, c = i & 63;
        int pos = ((c & 15) >> 1) * 8 + ((c >> 4) << 1) + (c & 1);
        ent_pi[(size_t)n * 64 + pos] = b;
        out[(size_t)n * OUT_STRIDE + c] = v;
    }
}

// ---------------------------------------------------------------------------
// K2: 3-phase multi-block exclusive scan counts -> row_ptr
// ---------------------------------------------------------------------------
__global__ __launch_bounds__(256) void scan1_kernel(
        const int* __restrict__ counts, int* __restrict__ excl,
        int* __restrict__ bsum, int n) {
    __shared__ int sh[256];
    int t = threadIdx.x;
    int i = blockIdx.x * 256 + t;
    int c = (i < n) ? counts[i] : 0;
    sh[t] = c;
    __syncthreads();
    for (int off = 1; off < 256; off <<= 1) {
        int v = (t >= off) ? sh[t - off] : 0;
        __syncthreads();
        sh[t] += v;
        __syncthreads();
    }
    if (i < n) excl[i] = sh[t] - c;
    if (t == 255) bsum[blockIdx.x] = sh[255];
}

__global__ __launch_bounds__(256) void scan2_kernel(
        const int* __restrict__ bsum, int* __restrict__ boff,
        int* __restrict__ row_ptr, int nb, int n) {
    __shared__ int sh[256];
    int t = threadIdx.x;
    int v = (t < nb) ? bsum[t] : 0;
    sh[t] = v;
    __syncthreads();
    for (int off = 1; off < 256; off <<= 1) {
        int x = (t >= off) ? sh[t - off] : 0;
        __syncthreads();
        sh[t] += x;
        __syncthreads();
    }
    if (t < nb) boff[t] = sh[t] - v;
    if (t == nb - 1) row_ptr[n] = sh[t];
}

// K3: finalize row_ptr AND scatter per-edge info into CSR ORDER:
//   einfo[pos] = src(16b) | dst(16b)<<16 | rel(4b)<<32
__global__ __launch_bounds__(256) void scan3_pos_kernel(
        const int* __restrict__ excl, const int* __restrict__ boff,
        int* __restrict__ row_ptr,
        const int* __restrict__ src, const int* __restrict__ dst,
        const int* __restrict__ etype, const int* __restrict__ off,
        unsigned long long* __restrict__ einfo) {
    int i = blockIdx.x * blockDim.x + threadIdx.x;
    if (i < N_ENT) row_ptr[i] = excl[i] + boff[i >> 8];
    if (i < N_EDGE) {
        int d = dst[i];
        int pos = excl[d] + boff[d >> 8] + off[i];
        unsigned long long info =
              (unsigned long long)(unsigned)src[i]
            | ((unsigned long long)(unsigned)d << 16)
            | ((unsigned long long)(unsigned)etype[i] << 32);
        einfo[pos] = info;
    }
}

// ---------------------------------------------------------------------------
// gz device body: Z_r = tanh(ent @ W_r + rel_r) @ W_r^T. NT dwordx4 Z stores
// (102 MB write-once stream — keep L2 hot for ent_pi/dst/counts).
// ---------------------------------------------------------------------------
__device__ __forceinline__ void gz_body(
        int r, int wid, int nw, int lane,
        const ushort* __restrict__ ent_pi,
        const float*  __restrict__ W_R,
        const float*  __restrict__ rel,
        ushort* __restrict__ Z,
        float* __restrict__ myLds) {
    int m = lane & 15;
    int q = lane >> 4;

    const float* Wr = W_R + (size_t)r * DIM * DIM;
    s16x8 b1[4][2], b2[4][2];
#pragma unroll
    for (int c = 0; c < 4; ++c)
#pragma unroll
        for (int ch = 0; ch < 2; ++ch)
#pragma unroll
            for (int j = 0; j < 8; ++j) {
                b1[c][ch][j] = (short)f2bf(Wr[pcol(ch * 32 + q * 8 + j) * DIM + c * 16 + m]);
                b2[c][ch][j] = (short)f2bf(Wr[(c * 16 + m) * DIM + ch * 32 + q * 8 + j]);
            }
    float relv[4];
#pragma unroll
    for (int c = 0; c < 4; ++c) relv[c] = rel[r * DIM + c * 16 + m];

    int par = m & 1;
    const int ntiles = N_ENT / 16;

    for (int t = wid; t < ntiles; t += nw) {
        int row0 = t * 16;
        const s16x8* arow = (const s16x8*)(ent_pi + (size_t)(row0 + m) * DIM);
        s16x8 a0 = arow[q];
        s16x8 a1 = arow[4 + q];
        f32x4 acc[4];
#pragma unroll
        for (int c = 0; c < 4; ++c) acc[c] = (f32x4){0.f, 0.f, 0.f, 0.f};
#pragma unroll
        for (int c = 0; c < 4; ++c) {
            acc[c] = __builtin_amdgcn_mfma_f32_16x16x32_bf16(a0, b1[c][0], acc[c], 0, 0, 0);
            acc[c] = __builtin_amdgcn_mfma_f32_16x16x32_bf16(a1, b1[c][1], acc[c], 0, 0, 0);
        }
#pragma unroll
        for (int c = 0; c < 4; ++c)
#pragma unroll
            for (int i = 0; i < 4; ++i) {
                float x = acc[c][i] + relv[c];
                float e2 = __expf(2.f * x);
                float g = 1.f - 2.f * __builtin_amdgcn_rcpf(e2 + 1.f);
                myLds[(q * 4 + i) * 68 + c * 16 + m] = g;
            }
        union { uint u[4]; s16x8 v; } a2u[2];
#pragma unroll
        for (int ch = 0; ch < 2; ++ch) {
            const f32x4* gp = (const f32x4*)(myLds + m * 68 + ch * 32 + q * 8);
            f32x4 g0 = gp[0];
            f32x4 g1 = gp[1];
            a2u[ch].u[0] = cvt_pk_bf16(g0[0], g0[1]);
            a2u[ch].u[1] = cvt_pk_bf16(g0[2], g0[3]);
            a2u[ch].u[2] = cvt_pk_bf16(g1[0], g1[1]);
            a2u[ch].u[3] = cvt_pk_bf16(g1[2], g1[3]);
        }

        f32x4 zacc[4];
#pragma unroll
        for (int c = 0; c < 4; ++c) zacc[c] = (f32x4){0.f, 0.f, 0.f, 0.f};
#pragma unroll
        for (int c = 0; c < 4; ++c) {
            zacc[c] = __builtin_amdgcn_mfma_f32_16x16x32_bf16(a2u[0].v, b2[c][0], zacc[c], 0, 0, 0);
            zacc[c] = __builtin_amdgcn_mfma_f32_16x16x32_bf16(a2u[1].v, b2[c][1], zacc[c], 0, 0, 0);
        }

        int rowA = row0 + 4 * q + (par ? 2 : 0);
        ushort* zb = Z + ((size_t)r * N_ENT + rowA) * 64 + (m >> 1) * 8;
#pragma unroll
        for (int rep = 0; rep < 2; ++rep) {
            u32x4 Wv;
#pragma unroll
            for (int c = 0; c < 4; ++c) {
                float send = par ? zacc[c][rep] : zacc[c][2 + rep];
                float own  = par ? zacc[c][2 + rep] : zacc[c][rep];
                float oth  = __shfl_xor(send, 1, 64);
                float lo = par ? oth : own;
                float hi = par ? own : oth;
                Wv[c] = cvt_pk_bf16(lo, hi);
            }
            __builtin_nontemporal_store(Wv, (u32x4*)(zb + rep * 64));
        }
    }
}

// ---------------------------------------------------------------------------
// F1: wave-specialized fusion (round-8/11 split — best measured). Waves 0-2:
// gz. Wave 3: histogram, 8 in-flight atomics/lane.
// ---------------------------------------------------------------------------
#define HIST_LANES 131072   // 2048 blocks * 64 lanes

__global__ __launch_bounds__(256, 4) void gz_hist_kernel(
        const ushort* __restrict__ ent_pi,
        const float*  __restrict__ W_R,
        const float*  __restrict__ rel,
        ushort* __restrict__ Z,
        const int* __restrict__ dst,
        int* __restrict__ counts,
        int* __restrict__ off) {
    __shared__ __align__(16) float lds[3][16 * 68 + 16];
    int lane = threadIdx.x & 63;
    int wv   = threadIdx.x >> 6;          // 0..3

    if (wv == 3) {
        int lane_gid = blockIdx.x * 64 + lane;
        int d[8]; bool v[8]; int o[8];
#pragma unroll
        for (int k = 0; k < 8; ++k) {
            int i = lane_gid + k * HIST_LANES;
            v[k] = (i < N_EDGE);
            d[k] = v[k] ? dst[i] : 0;
        }
#pragma unroll
        for (int k = 0; k < 8; ++k)
            if (v[k]) o[k] = atomicAdd(&counts[d[k]], 1);
#pragma unroll
        for (int k = 0; k < 8; ++k)
            if (v[k]) off[lane_gid + k * HIST_LANES] = o[k];
        return;
    }

    int r   = blockIdx.x >> 7;            // 128 blocks per relation
    int xb  = blockIdx.x & 127;
    int wid = xb * 3 + wv;                // [0,384)
    gz_body(r, wid, 384, lane, ent_pi, W_R, rel, Z, lds[wv]);
}

// ---------------------------------------------------------------------------
// K3b: per-edge logit = dot(ent_pi[s], Z[r][d]), edges streamed in CSR order.
// 64 edges/wave (8 per 8-lane subgroup) -> 16 gathers in flight. src side
// reads the small L2-resident ent_pi (the reason Z-form beats P-form).
// ---------------------------------------------------------------------------
__global__ __launch_bounds__(256) void att_dot_kernel(
        const ushort* __restrict__ ent_pi,
        const ushort* __restrict__ Z,
        const unsigned long long* __restrict__ einfo,
        uint2* __restrict__ es_csr,
        int n_edge) {
    int tid  = blockIdx.x * blockDim.x + threadIdx.x;
    int lane = threadIdx.x & 63;
    int sub  = lane >> 3;
    int q    = lane & 7;
    int base = (tid >> 6) * 64;
    if (base >= n_edge) return;

    int e[8];
    unsigned long long inf[8];
#pragma unroll
    for (int k = 0; k < 8; ++k) {
        e[k] = base + k * 8 + sub;
        inf[k] = (e[k] < n_edge) ? einfo[e[k]] : 0ull;
    }

    uint4 uz[8], ue[8];
#pragma unroll
    for (int k = 0; k < 8; ++k) {
        int s = (int)(inf[k] & 0xffffu);
        int d = (int)((inf[k] >> 16) & 0xffffu);
        int r = (int)((inf[k] >> 32) & 0xfu);
        uz[k] = *(const uint4*)(Z + ((size_t)r * N_ENT + d) * DIM + q * 8);
        ue[k] = *(const uint4*)(ent_pi + (size_t)s * DIM + q * 8);
    }

    float pr[8];
#pragma unroll
    for (int k = 0; k < 8; ++k) {
        float zv[8], ev[8];
        bf16x8_unpack(uz[k], zv);
        bf16x8_unpack(ue[k], ev);
        float p = 0.f;
#pragma unroll
        for (int j = 0; j < 8; ++j) p = fmaf(ev[j], zv[j], p);
        pr[k] = p;
    }
#pragma unroll
    for (int k = 0; k < 8; ++k) {
        pr[k] += __shfl_xor(pr[k], 1, 64);
        pr[k] += __shfl_xor(pr[k], 2, 64);
        pr[k] += __shfl_xor(pr[k], 4, 64);
    }

    if (q == 0) {
#pragma unroll
        for (int k = 0; k < 8; ++k)
            if (e[k] < n_edge)
                es_csr[e[k]] = make_uint2(__float_as_uint(pr[k]),
                                          (unsigned)(inf[k] & 0xffffu));
    }
}

// ---------------------------------------------------------------------------
// K6a-0: layer-0 aggregation with fused softmax stats. WRITES BACK the
// normalized weight a_e into es_csr.x so layers 1/2 skip stats+exp.
// ---------------------------------------------------------------------------
__global__ __launch_bounds__(256) void agg64s_kernel(
        const ushort* __restrict__ tab,      // [N][64] bf16
        uint2* __restrict__ es_csr,
        const int* __restrict__ row_ptr,
        float* __restrict__ N_h, int n_node) {
    int wid  = (blockIdx.x * blockDim.x + threadIdx.x) >> 6;
    int lane = threadIdx.x & 63;
    if (wid >= n_node) return;
    int q   = lane & 7;
    int sub = lane >> 3;

    int start = row_ptr[wid], end = row_ptr[wid + 1];

    // stats
    float mx = -INFINITY;
    for (int i = start + lane; i < end; i += 64)
        mx = fmaxf(mx, __uint_as_float(es_csr[i].x));
#pragma unroll
    for (int o = 32; o > 0; o >>= 1)
        mx = fmaxf(mx, __shfl_xor(mx, o, 64));
    float ssum = 0.f;
    for (int i = start + lane; i < end; i += 64)
        ssum += __expf(__uint_as_float(es_csr[i].x) - mx);
#pragma unroll
    for (int o = 32; o > 0; o >>= 1)
        ssum += __shfl_xor(ssum, o, 64);
    float inv = (end > start) ? (1.0f / ssum) : 0.f;

    // weighted gather + normalized-weight write-back
    float acc[8];
#pragma unroll
    for (int j = 0; j < 8; ++j) acc[j] = 0.f;

    for (int p = start + sub; p < end; p += 8) {
        uint2 es = es_csr[p];
        float av = __expf(__uint_as_float(es.x) - mx) * inv;
        int   si = (int)es.y;
        if (q == 0) es_csr[p].x = __float_as_uint(av);
        uint4 u  = *(const uint4*)(tab + (size_t)si * 64 + q * 8);
        float g[8];
        bf16x8_unpack(u, g);
#pragma unroll
        for (int j = 0; j < 8; ++j) acc[j] = fmaf(av, g[j], acc[j]);
    }
#pragma unroll
    for (int mask = 8; mask < 64; mask <<= 1)
#pragma unroll
        for (int j = 0; j < 8; ++j)
            acc[j] += __shfl_xor(acc[j], mask, 64);

    if (sub == 0) {
        float* dstp = N_h + (size_t)wid * 64 + q * 8;
        *(float4*)(dstp)     = (float4){acc[0], acc[1], acc[2], acc[3]};
        *(float4*)(dstp + 4) = (float4){acc[4], acc[5], acc[6], acc[7]};
    }
}

// ---------------------------------------------------------------------------
// K6a: 64-wide aggregation, pre-normalized weights (layer 1).
// ---------------------------------------------------------------------------
__global__ __launch_bounds__(256) void agg64_kernel(
        const ushort* __restrict__ tab,      // [N][64] bf16
        const uint2* __restrict__ es_csr,
        const int* __restrict__ row_ptr,
        float* __restrict__ N_h, int n_node) {
    int wid  = (blockIdx.x * blockDim.x + threadIdx.x) >> 6;
    int lane = threadIdx.x & 63;
    if (wid >= n_node) return;
    int q   = lane & 7;
    int sub = lane >> 3;

    int start = row_ptr[wid], end = row_ptr[wid + 1];
    float acc[8];
#pragma unroll
    for (int j = 0; j < 8; ++j) acc[j] = 0.f;

    for (int p = start + sub; p < end; p += 8) {
        uint2 es = es_csr[p];
        float av = __uint_as_float(es.x);
        int   si = (int)es.y;
        uint4 u  = *(const uint4*)(tab + (size_t)si * 64 + q * 8);
        float g[8];
        bf16x8_unpack(u, g);
#pragma unroll
        for (int j = 0; j < 8; ++j) acc[j] = fmaf(av, g[j], acc[j]);
    }
#pragma unroll
    for (int mask = 8; mask < 64; mask <<= 1)
#pragma unroll
        for (int j = 0; j < 8; ++j)
            acc[j] += __shfl_xor(acc[j], mask, 64);

    if (sub == 0) {
        float* dstp = N_h + (size_t)wid * 64 + q * 8;
        *(float4*)(dstp)     = (float4){acc[0], acc[1], acc[2], acc[3]};
        *(float4*)(dstp + 4) = (float4){acc[4], acc[5], acc[6], acc[7]};
    }
}

// K6a': 32-wide aggregation, pre-normalized weights (layer 2).
__global__ __launch_bounds__(256) void agg32_kernel(
        const ushort* __restrict__ tab,      // [N][32] bf16
        const uint2* __restrict__ es_csr,
        const int* __restrict__ row_ptr,
        float* __restrict__ N_h, int n_node) {
    int wid  = (blockIdx.x * blockDim.x + threadIdx.x) >> 6;
    int lane = threadIdx.x & 63;
    if (wid >= n_node) return;
    int q   = lane & 3;
    int sub = lane >> 2;

    int start = row_ptr[wid], end = row_ptr[wid + 1];
    float acc[8];
#pragma unroll
    for (int j = 0; j < 8; ++j) acc[j] = 0.f;

    for (int p = start + sub; p < end; p += 16) {
        uint2 es = es_csr[p];
        float av = __uint_as_float(es.x);
        int   si = (int)es.y;
        uint4 u  = *(const uint4*)(tab + (size_t)si * 32 + q * 8);
        float g[8];
        bf16x8_unpack(u, g);
#pragma unroll
        for (int j = 0; j < 8; ++j) acc[j] = fmaf(av, g[j], acc[j]);
    }
#pragma unroll
    for (int mask = 4; mask < 64; mask <<= 1)
#pragma unroll
        for (int j = 0; j < 8; ++j)
            acc[j] += __shfl_xor(acc[j], mask, 64);

    if (sub == 0) {
        float* dstp = N_h + (size_t)wid * 32 + q * 8;
        *(float4*)(dstp)     = (float4){acc[0], acc[1], acc[2], acc[3]};
        *(float4*)(dstp + 4) = (float4){acc[4], acc[5], acc[6], acc[7]};
    }
}

// ---------------------------------------------------------------------------
// K6b: dense bi-interaction MLP via MFMA, fused bias/leaky/l2-norm epilogue.
// ---------------------------------------------------------------------------
template <int D_IN, int D_OUT, bool PERM>
__global__ __launch_bounds__(256) void mlp_mfma_kernel(
        const ushort* __restrict__ h,        // [N][D_IN] bf16
        const float* __restrict__ N_h,       // [N][D_IN] f32
        const float* __restrict__ W1, const float* __restrict__ b1,
        const float* __restrict__ W2, const float* __restrict__ b2,
        ushort* __restrict__ ho,             // [N][D_OUT] bf16 (or null)
        float* __restrict__ out_buf, int out_col) {
    constexpr int CH = D_IN / 32;
    constexpr int CT = D_OUT / 16;

    int lane = threadIdx.x & 63;
    int m    = lane & 15;
    int q    = lane >> 4;
    int wid  = blockIdx.x * (blockDim.x >> 6) + (threadIdx.x >> 6);
    int nw   = gridDim.x * (blockDim.x >> 6);

    s16x8 bu[CT][CH], bv[CT][CH];
#pragma unroll
    for (int c = 0; c < CT; ++c)
#pragma unroll
        for (int ch = 0; ch < CH; ++ch)
#pragma unroll
            for (int j = 0; j < 8; ++j) {
                int p = ch * 32 + q * 8 + j;
                int k = PERM ? pcol(p) : p;
                bu[c][ch][j] = (short)f2bf(W1[k * D_OUT + c * 16 + m]);
                bv[c][ch][j] = (short)f2bf(W2[k * D_OUT + c * 16 + m]);
            }

    const int ntiles = N_ENT / 16;
    for (int t = wid; t < ntiles; t += nw) {
        int row0 = t * 16;
        s16x8 au[CH], av[CH];
#pragma unroll
        for (int ch = 0; ch < CH; ++ch) {
            uint4 hu = *(const uint4*)(h + (size_t)(row0 + m) * D_IN + ch * 32 + q * 8);
            float hv8[8];
            bf16x8_unpack(hu, hv8);
            const float4* np = (const float4*)(N_h + (size_t)(row0 + m) * D_IN + ch * 32 + q * 8);
            float4 na = np[0], nb = np[1];
            float nv[8] = {na.x, na.y, na.z, na.w, nb.x, nb.y, nb.z, nb.w};
#pragma unroll
            for (int j = 0; j < 8; ++j) {
                au[ch][j] = (short)f2bf(hv8[j] + nv[j]);
                av[ch][j] = (short)f2bf(hv8[j] * nv[j]);
            }
        }

        f32x4 accu[CT], accv[CT];
#pragma unroll
        for (int c = 0; c < CT; ++c) {
            accu[c] = (f32x4){0.f, 0.f, 0.f, 0.f};
            accv[c] = (f32x4){0.f, 0.f, 0.f, 0.f};
        }
#pragma unroll
        for (int c = 0; c < CT; ++c)
#pragma unroll
            for (int ch = 0; ch < CH; ++ch) {
                accu[c] = __builtin_amdgcn_mfma_f32_16x16x32_bf16(au[ch], bu[c][ch], accu[c], 0, 0, 0);
                accv[c] = __builtin_amdgcn_mfma_f32_16x16x32_bf16(av[ch], bv[c][ch], accv[c], 0, 0, 0);
            }

        float res[CT][4];
        float sq[4] = {0.f, 0.f, 0.f, 0.f};
#pragma unroll
        for (int c = 0; c < CT; ++c) {
            float bb1 = b1[c * 16 + m];
            float bb2 = b2[c * 16 + m];
#pragma unroll
            for (int i = 0; i < 4; ++i) {
                float o1 = accu[c][i] + bb1;
                float o2 = accv[c][i] + bb2;
                float r1 = (o1 >= 0.f) ? o1 : 0.01f * o1;
                float r2 = (o2 >= 0.f) ? o2 : 0.01f * o2;
                float rr = r1 + r2;
                res[c][i] = rr;
                sq[i] = fmaf(rr, rr, sq[i]);
            }
        }
#pragma unroll
        for (int mask = 1; mask < 16; mask <<= 1)
#pragma unroll
            for (int i = 0; i < 4; ++i)
                sq[i] += __shfl_xor(sq[i], mask, 64);

#pragma unroll
        for (int i = 0; i < 4; ++i) {
            int row = row0 + q * 4 + i;
            float inv = 1.f / fmaxf(sqrtf(sq[i]), 1e-12f);
#pragma unroll
            for (int c = 0; c < CT; ++c) {
                int col = c * 16 + m;
                out_buf[(size_t)row * OUT_STRIDE + out_col + col] = res[c][i] * inv;
                if (ho) ho[(size_t)row * D_OUT + col] = f2bf(res[c][i]);
            }
        }
    }
}

// ---------------------------------------------------------------------------
extern "C" void kernel_launch(void* const* d_in, const int* in_sizes, int n_in,
                              void* d_out, int out_size, void* d_ws, size_t ws_size,
                              hipStream_t stream) {
    const float* ent  = (const float*)d_in[0];
    const float* rel  = (const float*)d_in[1];
    const float* W_R  = (const float*)d_in[2];
    const float* W1_0 = (const float*)d_in[3];
    const float* b1_0 = (const float*)d_in[4];
    const float* W2_0 = (const float*)d_in[5];
    const float* b2_0 = (const float*)d_in[6];
    const float* W1_1 = (const float*)d_in[7];
    const float* b1_1 = (const float*)d_in[8];
    const float* W2_1 = (const float*)d_in[9];
    const float* b2_1 = (const float*)d_in[10];
    const float* W1_2 = (const float*)d_in[11];
    const float* b1_2 = (const float*)d_in[12];
    const float* W2_2 = (const float*)d_in[13];
    const float* b2_2 = (const float*)d_in[14];
    const int*   src   = (const int*)d_in[15];
    const int*   dst   = (const int*)d_in[16];
    const int*   etype = (const int*)d_in[17];
    float* out = (float*)d_out;

    // workspace layout
    char* w = (char*)d_ws;
    uint2*  es_csr  = (uint2*)w;  w += (size_t)N_EDGE * 8;              // 8 MB packed
    int*    counts  = (int*)w;    w += (size_t)(N_ENT + 64) * 4;
    int*    row_ptr = (int*)w;    w += (size_t)(N_ENT + 64) * 4;
    int*    excl    = (int*)w;    w += (size_t)(N_ENT + 64) * 4;
    int*    bsum    = (int*)w;    w += 256 * 4;
    int*    boff    = (int*)w;    w += 256 * 4;
    ushort* ent_pi  = (ushort*)w; w += (size_t)N_ENT * 64 * 2;          // 6.4 MB
    ushort* h1      = (ushort*)w; w += (size_t)N_ENT * 64 * 2;          // 6.4 MB
    ushort* h2      = (ushort*)w; w += (size_t)N_ENT * 32 * 2;          // 3.2 MB
    float*  N_h     = (float*)w;  w += (size_t)N_ENT * 64 * 4;          // 12.8 MB
    ushort* Z       = (ushort*)w;                                       // 102 MB
    (void)ws_size;

    // stream-ordered overlays:
    //  - off lives in the es_csr region: written by gz_hist, read by
    //    scan3_pos, dead before att_dot writes es_csr.
    //  - einfo lives in the N_h region: written by scan3_pos, read by
    //    att_dot, dead before agg writes N_h.
    int* off = (int*)es_csr;
    unsigned long long* einfo = (unsigned long long*)N_h;

    (void)hipMemsetAsync(counts, 0, (size_t)N_ENT * 4, stream);

    const int nb = (N_ENT + 255) / 256;

    prep_convert_kernel<<<(N_ENT * DIM + 255) / 256, 256, 0, stream>>>(
        ent, ent_pi, out);

    // F1: full gz (waves 0-2) || edge histogram (wave 3).
    gz_hist_kernel<<<2048, 256, 0, stream>>>(
        ent_pi, W_R, rel, Z, dst, counts, off);

    scan1_kernel<<<nb, 256, 0, stream>>>(counts, excl, bsum, N_ENT);
    scan2_kernel<<<1, 256, 0, stream>>>(bsum, boff, row_ptr, nb, N_ENT);
    scan3_pos_kernel<<<(N_EDGE + 255) / 256, 256, 0, stream>>>(
        excl, boff, row_ptr, src, dst, etype, off, einfo);

    att_dot_kernel<<<((N_EDGE + 63) / 64 * 64 + 255) / 256, 256, 0, stream>>>(
        ent_pi, Z, einfo, es_csr, N_EDGE);

    const int aggGrid = (N_ENT + 3) / 4;
    const int mlpGrid = 782;

    // ---- layer 0: agg with fused stats + a_e write-back ----
    agg64s_kernel<<<aggGrid, 256, 0, stream>>>(ent_pi, es_csr, row_ptr, N_h, N_ENT);
    mlp_mfma_kernel<64, 64, true><<<mlpGrid, 256, 0, stream>>>(
        ent_pi, N_h, W1_0, b1_0, W2_0, b2_0, h1, out, 64);

    // ---- layer 1: D_IN=64 (h1) -> D_OUT=32 (h2) ----
    agg64_kernel<<<aggGrid, 256, 0, stream>>>(h1, es_csr, row_ptr, N_h, N_ENT);
    mlp_mfma_kernel<64, 32, false><<<mlpGrid, 256, 0, stream>>>(
        h1, N_h, W1_1, b1_1, W2_1, b2_1, h2, out, 128);

    // ---- layer 2: D_IN=32 (h2) -> D_OUT=16 ----
    agg32_kernel<<<aggGrid, 256, 0, stream>>>(h2, es_csr, row_ptr, N_h, N_ENT);
    mlp_mfma_kernel<32, 16, false><<<mlpGrid, 256, 0, stream>>>(
        h2, N_h, W1_2, b1_2, W2_2, b2_2, nullptr, out, 160);
}

// Round 15
// 356.914 us; speedup vs baseline: 1.1680x; 1.0171x over previous
//
#include <hip/hip_runtime.h>
#include <hip/hip_bf16.h>
#include <cmath>

#define N_ENT  50000
#define N_RELS 16
#define N_EDGE 1000000
#define DIM    64
#define OUT_STRIDE 176

typedef float f32x4 __attribute__((ext_vector_type(4)));
typedef short s16x8 __attribute__((ext_vector_type(8)));
typedef uint  u32x4 __attribute__((ext_vector_type(4)));

__device__ inline void bf16x8_unpack(uint4 u, float* f) {
    f[0] = __uint_as_float((u.x & 0xffffu) << 16);
    f[1] = __uint_as_float(u.x & 0xffff0000u);
    f[2] = __uint_as_float((u.y & 0xffffu) << 16);
    f[3] = __uint_as_float(u.y & 0xffff0000u);
    f[4] = __uint_as_float((u.z & 0xffffu) << 16);
    f[5] = __uint_as_float(u.z & 0xffff0000u);
    f[6] = __uint_as_float((u.w & 0xffffu) << 16);
    f[7] = __uint_as_float(u.w & 0xffff0000u);
}

__device__ inline ushort f2bf(float x) {
    __hip_bfloat16 b = __float2bfloat16(x);
    return *(ushort*)&b;
}

__device__ inline uint cvt_pk_bf16(float lo, float hi) {
    uint r;
    asm("v_cvt_pk_bf16_f32 %0, %1, %2" : "=v"(r) : "v"(lo), "v"(hi));
    return r;
}

// Column permutation for the packed-Z / ent_pi layout.
__device__ __host__ inline int pcol(int p) {
    int qp = (p >> 3) & 7;
    int k  = p & 7;
    return 16 * (k >> 1) + 2 * qp + (k & 1);
}

// ---------------------------------------------------------------------------
// K0a: streaming prep only — ent fp32 -> permuted bf16 table + out[:,0:64].
// ---------------------------------------------------------------------------
__global__ __launch_bounds__(256) void prep_convert_kernel(
        const float* __restrict__ ent,
        ushort* __restrict__ ent_pi,
        float* __restrict__ out) {
    int i = blockIdx.x * blockDim.x + threadIdx.x;
    if (i < N_ENT * DIM) {
        float v = ent[i];
        ushort b = f2bf(v);
        int n = i >> 6, c = i & 63;
        int pos = ((c & 15) >> 1) * 8 + ((c >> 4) << 1) + (c & 1);
        ent_pi[(size_t)n * 64 + pos] = b;
        out[(size_t)n * OUT_STRIDE + c] = v;
    }
}

// ---------------------------------------------------------------------------
// K2: 3-phase multi-block exclusive scan counts -> row_ptr
// ---------------------------------------------------------------------------
__global__ __launch_bounds__(256) void scan1_kernel(
        const int* __restrict__ counts, int* __restrict__ excl,
        int* __restrict__ bsum, int n) {
    __shared__ int sh[256];
    int t = threadIdx.x;
    int i = blockIdx.x * 256 + t;
    int c = (i < n) ? counts[i] : 0;
    sh[t] = c;
    __syncthreads();
    for (int off = 1; off < 256; off <<= 1) {
        int v = (t >= off) ? sh[t - off] : 0;
        __syncthreads();
        sh[t] += v;
        __syncthreads();
    }
    if (i < n) excl[i] = sh[t] - c;
    if (t == 255) bsum[blockIdx.x] = sh[255];
}

__global__ __launch_bounds__(256) void scan2_kernel(
        const int* __restrict__ bsum, int* __restrict__ boff,
        int* __restrict__ row_ptr, int nb, int n) {
    __shared__ int sh[256];
    int t = threadIdx.x;
    int v = (t < nb) ? bsum[t] : 0;
    sh[t] = v;
    __syncthreads();
    for (int off = 1; off < 256; off <<= 1) {
        int x = (t >= off) ? sh[t - off] : 0;
        __syncthreads();
        sh[t] += x;
        __syncthreads();
    }
    if (t < nb) boff[t] = sh[t] - v;
    if (t == nb - 1) row_ptr[n] = sh[t];
}

// K3: finalize row_ptr AND scatter per-edge info into CSR ORDER:
//   einfo[pos] = src(16b) | dst(16b)<<16 | rel(4b)<<32
__global__ __launch_bounds__(256) void scan3_pos_kernel(
        const int* __restrict__ excl, const int* __restrict__ boff,
        int* __restrict__ row_ptr,
        const int* __restrict__ src, const int* __restrict__ dst,
        const int* __restrict__ etype, const int* __restrict__ off,
        unsigned long long* __restrict__ einfo) {
    int i = blockIdx.x * blockDim.x + threadIdx.x;
    if (i < N_ENT) row_ptr[i] = excl[i] + boff[i >> 8];
    if (i < N_EDGE) {
        int d = dst[i];
        int pos = excl[d] + boff[d >> 8] + off[i];
        unsigned long long info =
              (unsigned long long)(unsigned)src[i]
            | ((unsigned long long)(unsigned)d << 16)
            | ((unsigned long long)(unsigned)etype[i] << 32);
        einfo[pos] = info;
    }
}

// ---------------------------------------------------------------------------
// gz device body: Z_r = tanh(ent @ W_r + rel_r) @ W_r^T. NT dwordx4 Z stores
// (102 MB write-once stream — keep L2 hot for ent_pi/dst/counts).
// ---------------------------------------------------------------------------
__device__ __forceinline__ void gz_body(
        int r, int wid, int nw, int lane,
        const ushort* __restrict__ ent_pi,
        const float*  __restrict__ W_R,
        const float*  __restrict__ rel,
        ushort* __restrict__ Z,
        float* __restrict__ myLds) {
    int m = lane & 15;
    int q = lane >> 4;

    const float* Wr = W_R + (size_t)r * DIM * DIM;
    s16x8 b1[4][2], b2[4][2];
#pragma unroll
    for (int c = 0; c < 4; ++c)
#pragma unroll
        for (int ch = 0; ch < 2; ++ch)
#pragma unroll
            for (int j = 0; j < 8; ++j) {
                b1[c][ch][j] = (short)f2bf(Wr[pcol(ch * 32 + q * 8 + j) * DIM + c * 16 + m]);
                b2[c][ch][j] = (short)f2bf(Wr[(c * 16 + m) * DIM + ch * 32 + q * 8 + j]);
            }
    float relv[4];
#pragma unroll
    for (int c = 0; c < 4; ++c) relv[c] = rel[r * DIM + c * 16 + m];

    int par = m & 1;
    const int ntiles = N_ENT / 16;

    for (int t = wid; t < ntiles; t += nw) {
        int row0 = t * 16;
        const s16x8* arow = (const s16x8*)(ent_pi + (size_t)(row0 + m) * DIM);
        s16x8 a0 = arow[q];
        s16x8 a1 = arow[4 + q];
        f32x4 acc[4];
#pragma unroll
        for (int c = 0; c < 4; ++c) acc[c] = (f32x4){0.f, 0.f, 0.f, 0.f};
#pragma unroll
        for (int c = 0; c < 4; ++c) {
            acc[c] = __builtin_amdgcn_mfma_f32_16x16x32_bf16(a0, b1[c][0], acc[c], 0, 0, 0);
            acc[c] = __builtin_amdgcn_mfma_f32_16x16x32_bf16(a1, b1[c][1], acc[c], 0, 0, 0);
        }
#pragma unroll
        for (int c = 0; c < 4; ++c)
#pragma unroll
            for (int i = 0; i < 4; ++i) {
                float x = acc[c][i] + relv[c];
                float e2 = __expf(2.f * x);
                float g = 1.f - 2.f * __builtin_amdgcn_rcpf(e2 + 1.f);
                myLds[(q * 4 + i) * 68 + c * 16 + m] = g;
            }
        union { uint u[4]; s16x8 v; } a2u[2];
#pragma unroll
        for (int ch = 0; ch < 2; ++ch) {
            const f32x4* gp = (const f32x4*)(myLds + m * 68 + ch * 32 + q * 8);
            f32x4 g0 = gp[0];
            f32x4 g1 = gp[1];
            a2u[ch].u[0] = cvt_pk_bf16(g0[0], g0[1]);
            a2u[ch].u[1] = cvt_pk_bf16(g0[2], g0[3]);
            a2u[ch].u[2] = cvt_pk_bf16(g1[0], g1[1]);
            a2u[ch].u[3] = cvt_pk_bf16(g1[2], g1[3]);
        }

        f32x4 zacc[4];
#pragma unroll
        for (int c = 0; c < 4; ++c) zacc[c] = (f32x4){0.f, 0.f, 0.f, 0.f};
#pragma unroll
        for (int c = 0; c < 4; ++c) {
            zacc[c] = __builtin_amdgcn_mfma_f32_16x16x32_bf16(a2u[0].v, b2[c][0], zacc[c], 0, 0, 0);
            zacc[c] = __builtin_amdgcn_mfma_f32_16x16x32_bf16(a2u[1].v, b2[c][1], zacc[c], 0, 0, 0);
        }

        int rowA = row0 + 4 * q + (par ? 2 : 0);
        ushort* zb = Z + ((size_t)r * N_ENT + rowA) * 64 + (m >> 1) * 8;
#pragma unroll
        for (int rep = 0; rep < 2; ++rep) {
            u32x4 Wv;
#pragma unroll
            for (int c = 0; c < 4; ++c) {
                float send = par ? zacc[c][rep] : zacc[c][2 + rep];
                float own  = par ? zacc[c][2 + rep] : zacc[c][rep];
                float oth  = __shfl_xor(send, 1, 64);
                float lo = par ? oth : own;
                float hi = par ? own : oth;
                Wv[c] = cvt_pk_bf16(lo, hi);
            }
            __builtin_nontemporal_store(Wv, (u32x4*)(zb + rep * 64));
        }
    }
}

// ---------------------------------------------------------------------------
// F1: wave-specialized fusion (round-8 split, the best measured). 2048
// blocks x 256 threads. Waves 0-2: full gz (384 waves/relation). Wave 3:
// histogram, 8 edges/lane in ONE batch (max fabric concurrency).
// ---------------------------------------------------------------------------
#define HIST_LANES 131072   // 2048 blocks * 64 lanes

__global__ __launch_bounds__(256, 4) void gz_hist_kernel(
        const ushort* __restrict__ ent_pi,
        const float*  __restrict__ W_R,
        const float*  __restrict__ rel,
        ushort* __restrict__ Z,
        const int* __restrict__ dst,
        int* __restrict__ counts,
        int* __restrict__ off) {
    __shared__ __align__(16) float lds[3][16 * 68 + 16];
    int lane = threadIdx.x & 63;
    int wv   = threadIdx.x >> 6;          // 0..3

    if (wv == 3) {
        int lane_gid = blockIdx.x * 64 + lane;
        int d[8]; bool v[8]; int o[8];
#pragma unroll
        for (int k = 0; k < 8; ++k) {
            int i = lane_gid + k * HIST_LANES;
            v[k] = (i < N_EDGE);
            d[k] = v[k] ? dst[i] : 0;
        }
#pragma unroll
        for (int k = 0; k < 8; ++k)
            if (v[k]) o[k] = atomicAdd(&counts[d[k]], 1);
#pragma unroll
        for (int k = 0; k < 8; ++k)
            if (v[k]) off[lane_gid + k * HIST_LANES] = o[k];
        return;
    }

    int r   = blockIdx.x >> 7;            // 128 blocks per relation
    int xb  = blockIdx.x & 127;
    int wid = xb * 3 + wv;                // [0,384)
    gz_body(r, wid, 384, lane, ent_pi, W_R, rel, Z, lds[wv]);
}

// ---------------------------------------------------------------------------
// K3b: per-edge logit = dot(ent_pi[s], Z[r][d]), edges streamed in CSR order.
// 64 edges/wave (8 per 8-lane subgroup) -> 16 gathers in flight.
// ---------------------------------------------------------------------------
__global__ __launch_bounds__(256) void att_dot_kernel(
        const ushort* __restrict__ ent_pi,
        const ushort* __restrict__ Z,
        const unsigned long long* __restrict__ einfo,
        uint2* __restrict__ es_csr,
        int n_edge) {
    int tid  = blockIdx.x * blockDim.x + threadIdx.x;
    int lane = threadIdx.x & 63;
    int sub  = lane >> 3;
    int q    = lane & 7;
    int base = (tid >> 6) * 64;
    if (base >= n_edge) return;

    int e[8];
    unsigned long long inf[8];
#pragma unroll
    for (int k = 0; k < 8; ++k) {
        e[k] = base + k * 8 + sub;
        inf[k] = (e[k] < n_edge) ? einfo[e[k]] : 0ull;
    }

    uint4 uz[8], ue[8];
#pragma unroll
    for (int k = 0; k < 8; ++k) {
        int s = (int)(inf[k] & 0xffffu);
        int d = (int)((inf[k] >> 16) & 0xffffu);
        int r = (int)((inf[k] >> 32) & 0xfu);
        uz[k] = *(const uint4*)(Z + ((size_t)r * N_ENT + d) * DIM + q * 8);
        ue[k] = *(const uint4*)(ent_pi + (size_t)s * DIM + q * 8);
    }

    float pr[8];
#pragma unroll
    for (int k = 0; k < 8; ++k) {
        float zv[8], ev[8];
        bf16x8_unpack(uz[k], zv);
        bf16x8_unpack(ue[k], ev);
        float p = 0.f;
#pragma unroll
        for (int j = 0; j < 8; ++j) p = fmaf(ev[j], zv[j], p);
        pr[k] = p;
    }
#pragma unroll
    for (int k = 0; k < 8; ++k) {
        pr[k] += __shfl_xor(pr[k], 1, 64);
        pr[k] += __shfl_xor(pr[k], 2, 64);
        pr[k] += __shfl_xor(pr[k], 4, 64);
    }

    if (q == 0) {
#pragma unroll
        for (int k = 0; k < 8; ++k)
            if (e[k] < n_edge)
                es_csr[e[k]] = make_uint2(__float_as_uint(pr[k]),
                                          (unsigned)(inf[k] & 0xffffu));
    }
}

// ---------------------------------------------------------------------------
// K6a-0: layer-0 aggregation with FUSED softmax stats.
// ---------------------------------------------------------------------------
__global__ __launch_bounds__(256) void agg64s_kernel(
        const ushort* __restrict__ tab,      // [N][64] bf16
        const uint2* __restrict__ es_csr,
        const int* __restrict__ row_ptr,
        float2* __restrict__ stats,
        float* __restrict__ N_h, int n_node) {
    int wid  = (blockIdx.x * blockDim.x + threadIdx.x) >> 6;
    int lane = threadIdx.x & 63;
    if (wid >= n_node) return;
    int q   = lane & 7;
    int sub = lane >> 3;

    int start = row_ptr[wid], end = row_ptr[wid + 1];

    // pass 1: stats
    float mx = -INFINITY;
    for (int i = start + lane; i < end; i += 64)
        mx = fmaxf(mx, __uint_as_float(es_csr[i].x));
#pragma unroll
    for (int o = 32; o > 0; o >>= 1)
        mx = fmaxf(mx, __shfl_xor(mx, o, 64));
    float ssum = 0.f;
    for (int i = start + lane; i < end; i += 64)
        ssum += __expf(__uint_as_float(es_csr[i].x) - mx);
#pragma unroll
    for (int o = 32; o > 0; o >>= 1)
        ssum += __shfl_xor(ssum, o, 64);
    float inv = (end > start) ? (1.0f / ssum) : 0.f;
    if (lane == 0) stats[wid] = make_float2(mx, inv);

    // pass 2: weighted gather
    float acc[8];
#pragma unroll
    for (int j = 0; j < 8; ++j) acc[j] = 0.f;

    for (int p = start + sub; p < end; p += 8) {
        uint2 es = es_csr[p];
        float av = __expf(__uint_as_float(es.x) - mx);
        int   si = (int)es.y;
        uint4 u  = *(const uint4*)(tab + (size_t)si * 64 + q * 8);
        float g[8];
        bf16x8_unpack(u, g);
#pragma unroll
        for (int j = 0; j < 8; ++j) acc[j] = fmaf(av, g[j], acc[j]);
    }
#pragma unroll
    for (int mask = 8; mask < 64; mask <<= 1)
#pragma unroll
        for (int j = 0; j < 8; ++j)
            acc[j] += __shfl_xor(acc[j], mask, 64);

    if (sub == 0) {
        float* dstp = N_h + (size_t)wid * 64 + q * 8;
        *(float4*)(dstp)     = (float4){acc[0] * inv, acc[1] * inv, acc[2] * inv, acc[3] * inv};
        *(float4*)(dstp + 4) = (float4){acc[4] * inv, acc[5] * inv, acc[6] * inv, acc[7] * inv};
    }
}

// ---------------------------------------------------------------------------
// K6a: fused 64-wide aggregation (layers >=1, stats precomputed).
// ---------------------------------------------------------------------------
__global__ __launch_bounds__(256) void agg64_kernel(
        const ushort* __restrict__ tab,      // [N][64] bf16
        const uint2* __restrict__ es_csr,
        const int* __restrict__ row_ptr,
        const float2* __restrict__ stats,
        float* __restrict__ N_h, int n_node) {
    int wid  = (blockIdx.x * blockDim.x + threadIdx.x) >> 6;
    int lane = threadIdx.x & 63;
    if (wid >= n_node) return;
    int q   = lane & 7;
    int sub = lane >> 3;

    int start = row_ptr[wid], end = row_ptr[wid + 1];
    float2 st = stats[wid];
    float mx = st.x, inv = st.y;
    float acc[8];
#pragma unroll
    for (int j = 0; j < 8; ++j) acc[j] = 0.f;

    for (int p = start + sub; p < end; p += 8) {
        uint2 es = es_csr[p];
        float av = __expf(__uint_as_float(es.x) - mx);
        int   si = (int)es.y;
        uint4 u  = *(const uint4*)(tab + (size_t)si * 64 + q * 8);
        float g[8];
        bf16x8_unpack(u, g);
#pragma unroll
        for (int j = 0; j < 8; ++j) acc[j] = fmaf(av, g[j], acc[j]);
    }
#pragma unroll
    for (int mask = 8; mask < 64; mask <<= 1)
#pragma unroll
        for (int j = 0; j < 8; ++j)
            acc[j] += __shfl_xor(acc[j], mask, 64);

    if (sub == 0) {
        float* dstp = N_h + (size_t)wid * 64 + q * 8;
        *(float4*)(dstp)     = (float4){acc[0] * inv, acc[1] * inv, acc[2] * inv, acc[3] * inv};
        *(float4*)(dstp + 4) = (float4){acc[4] * inv, acc[5] * inv, acc[6] * inv, acc[7] * inv};
    }
}

// K6a': 32-wide aggregation for layer 2.
__global__ __launch_bounds__(256) void agg32_kernel(
        const ushort* __restrict__ tab,      // [N][32] bf16
        const uint2* __restrict__ es_csr,
        const int* __restrict__ row_ptr,
        const float2* __restrict__ stats,
        float* __restrict__ N_h, int n_node) {
    int wid  = (blockIdx.x * blockDim.x + threadIdx.x) >> 6;
    int lane = threadIdx.x & 63;
    if (wid >= n_node) return;
    int q   = lane & 3;
    int sub = lane >> 2;

    int start = row_ptr[wid], end = row_ptr[wid + 1];
    float2 st = stats[wid];
    float mx = st.x, inv = st.y;
    float acc[8];
#pragma unroll
    for (int j = 0; j < 8; ++j) acc[j] = 0.f;

    for (int p = start + sub; p < end; p += 16) {
        uint2 es = es_csr[p];
        float av = __expf(__uint_as_float(es.x) - mx);
        int   si = (int)es.y;
        uint4 u  = *(const uint4*)(tab + (size_t)si * 32 + q * 8);
        float g[8];
        bf16x8_unpack(u, g);
#pragma unroll
        for (int j = 0; j < 8; ++j) acc[j] = fmaf(av, g[j], acc[j]);
    }
#pragma unroll
    for (int mask = 4; mask < 64; mask <<= 1)
#pragma unroll
        for (int j = 0; j < 8; ++j)
            acc[j] += __shfl_xor(acc[j], mask, 64);

    if (sub == 0) {
        float* dstp = N_h + (size_t)wid * 32 + q * 8;
        *(float4*)(dstp)     = (float4){acc[0] * inv, acc[1] * inv, acc[2] * inv, acc[3] * inv};
        *(float4*)(dstp + 4) = (float4){acc[4] * inv, acc[5] * inv, acc[6] * inv, acc[7] * inv};
    }
}

// ---------------------------------------------------------------------------
// K6b: dense bi-interaction MLP via MFMA, fused bias/leaky/l2-norm epilogue.
// ---------------------------------------------------------------------------
template <int D_IN, int D_OUT, bool PERM>
__global__ __launch_bounds__(256) void mlp_mfma_kernel(
        const ushort* __restrict__ h,        // [N][D_IN] bf16
        const float* __restrict__ N_h,       // [N][D_IN] f32
        const float* __restrict__ W1, const float* __restrict__ b1,
        const float* __restrict__ W2, const float* __restrict__ b2,
        ushort* __restrict__ ho,             // [N][D_OUT] bf16 (or null)
        float* __restrict__ out_buf, int out_col) {
    constexpr int CH = D_IN / 32;
    constexpr int CT = D_OUT / 16;

    int lane = threadIdx.x & 63;
    int m    = lane & 15;
    int q    = lane >> 4;
    int wid  = blockIdx.x * (blockDim.x >> 6) + (threadIdx.x >> 6);
    int nw   = gridDim.x * (blockDim.x >> 6);

    s16x8 bu[CT][CH], bv[CT][CH];
#pragma unroll
    for (int c = 0; c < CT; ++c)
#pragma unroll
        for (int ch = 0; ch < CH; ++ch)
#pragma unroll
            for (int j = 0; j < 8; ++j) {
                int p = ch * 32 + q * 8 + j;
                int k = PERM ? pcol(p) : p;
                bu[c][ch][j] = (short)f2bf(W1[k * D_OUT + c * 16 + m]);
                bv[c][ch][j] = (short)f2bf(W2[k * D_OUT + c * 16 + m]);
            }

    const int ntiles = N_ENT / 16;
    for (int t = wid; t < ntiles; t += nw) {
        int row0 = t * 16;
        s16x8 au[CH], av[CH];
#pragma unroll
        for (int ch = 0; ch < CH; ++ch) {
            uint4 hu = *(const uint4*)(h + (size_t)(row0 + m) * D_IN + ch * 32 + q * 8);
            float hv8[8];
            bf16x8_unpack(hu, hv8);
            const float4* np = (const float4*)(N_h + (size_t)(row0 + m) * D_IN + ch * 32 + q * 8);
            float4 na = np[0], nb = np[1];
            float nv[8] = {na.x, na.y, na.z, na.w, nb.x, nb.y, nb.z, nb.w};
#pragma unroll
            for (int j = 0; j < 8; ++j) {
                au[ch][j] = (short)f2bf(hv8[j] + nv[j]);
                av[ch][j] = (short)f2bf(hv8[j] * nv[j]);
            }
        }

        f32x4 accu[CT], accv[CT];
#pragma unroll
        for (int c = 0; c < CT; ++c) {
            accu[c] = (f32x4){0.f, 0.f, 0.f, 0.f};
            accv[c] = (f32x4){0.f, 0.f, 0.f, 0.f};
        }
#pragma unroll
        for (int c = 0; c < CT; ++c)
#pragma unroll
            for (int ch = 0; ch < CH; ++ch) {
                accu[c] = __builtin_amdgcn_mfma_f32_16x16x32_bf16(au[ch], bu[c][ch], accu[c], 0, 0, 0);
                accv[c] = __builtin_amdgcn_mfma_f32_16x16x32_bf16(av[ch], bv[c][ch], accv[c], 0, 0, 0);
            }

        float res[CT][4];
        float sq[4] = {0.f, 0.f, 0.f, 0.f};
#pragma unroll
        for (int c = 0; c < CT; ++c) {
            float bb1 = b1[c * 16 + m];
            float bb2 = b2[c * 16 + m];
#pragma unroll
            for (int i = 0; i < 4; ++i) {
                float o1 = accu[c][i] + bb1;
                float o2 = accv[c][i] + bb2;
                float r1 = (o1 >= 0.f) ? o1 : 0.01f * o1;
                float r2 = (o2 >= 0.f) ? o2 : 0.01f * o2;
                float rr = r1 + r2;
                res[c][i] = rr;
                sq[i] = fmaf(rr, rr, sq[i]);
            }
        }
#pragma unroll
        for (int mask = 1; mask < 16; mask <<= 1)
#pragma unroll
            for (int i = 0; i < 4; ++i)
                sq[i] += __shfl_xor(sq[i], mask, 64);

#pragma unroll
        for (int i = 0; i < 4; ++i) {
            int row = row0 + q * 4 + i;
            float inv = 1.f / fmaxf(sqrtf(sq[i]), 1e-12f);
#pragma unroll
            for (int c = 0; c < CT; ++c) {
                int col = c * 16 + m;
                out_buf[(size_t)row * OUT_STRIDE + out_col + col] = res[c][i] * inv;
                if (ho) ho[(size_t)row * D_OUT + col] = f2bf(res[c][i]);
            }
        }
    }
}

// ---------------------------------------------------------------------------
extern "C" void kernel_launch(void* const* d_in, const int* in_sizes, int n_in,
                              void* d_out, int out_size, void* d_ws, size_t ws_size,
                              hipStream_t stream) {
    const float* ent  = (const float*)d_in[0];
    const float* rel  = (const float*)d_in[1];
    const float* W_R  = (const float*)d_in[2];
    const float* W1_0 = (const float*)d_in[3];
    const float* b1_0 = (const float*)d_in[4];
    const float* W2_0 = (const float*)d_in[5];
    const float* b2_0 = (const float*)d_in[6];
    const float* W1_1 = (const float*)d_in[7];
    const float* b1_1 = (const float*)d_in[8];
    const float* W2_1 = (const float*)d_in[9];
    const float* b2_1 = (const float*)d_in[10];
    const float* W1_2 = (const float*)d_in[11];
    const float* b1_2 = (const float*)d_in[12];
    const float* W2_2 = (const float*)d_in[13];
    const float* b2_2 = (const float*)d_in[14];
    const int*   src   = (const int*)d_in[15];
    const int*   dst   = (const int*)d_in[16];
    const int*   etype = (const int*)d_in[17];
    float* out = (float*)d_out;

    // workspace layout
    char* w = (char*)d_ws;
    uint2*  es_csr  = (uint2*)w;  w += (size_t)N_EDGE * 8;              // 8 MB packed
    int*    counts  = (int*)w;    w += (size_t)(N_ENT + 64) * 4;
    int*    row_ptr = (int*)w;    w += (size_t)(N_ENT + 64) * 4;
    float2* stats   = (float2*)w; w += (size_t)(N_ENT + 64) * 8;
    int*    excl    = (int*)w;    w += (size_t)(N_ENT + 64) * 4;
    int*    bsum    = (int*)w;    w += 256 * 4;
    int*    boff    = (int*)w;    w += 256 * 4;
    ushort* ent_pi  = (ushort*)w; w += (size_t)N_ENT * 64 * 2;          // 6.4 MB
    ushort* h1      = (ushort*)w; w += (size_t)N_ENT * 64 * 2;          // 6.4 MB
    ushort* h2      = (ushort*)w; w += (size_t)N_ENT * 32 * 2;          // 3.2 MB
    float*  N_h     = (float*)w;  w += (size_t)N_ENT * 64 * 4;          // 12.8 MB
    ushort* Z       = (ushort*)w;                                       // 102 MB
    (void)ws_size;

    // stream-ordered overlays:
    //  - off lives in the es_csr region: written by gz_hist, read by
    //    scan3_pos, dead before att_dot writes es_csr.
    //  - einfo lives in the N_h region: written by scan3_pos, read by
    //    att_dot, dead before agg writes N_h.
    int* off = (int*)es_csr;
    unsigned long long* einfo = (unsigned long long*)N_h;

    (void)hipMemsetAsync(counts, 0, (size_t)N_ENT * 4, stream);

    const int nb = (N_ENT + 255) / 256;

    prep_convert_kernel<<<(N_ENT * DIM + 255) / 256, 256, 0, stream>>>(
        ent, ent_pi, out);

    // F1: full gz (waves 0-2) || edge histogram (wave 3).
    gz_hist_kernel<<<2048, 256, 0, stream>>>(
        ent_pi, W_R, rel, Z, dst, counts, off);

    scan1_kernel<<<nb, 256, 0, stream>>>(counts, excl, bsum, N_ENT);
    scan2_kernel<<<1, 256, 0, stream>>>(bsum, boff, row_ptr, nb, N_ENT);
    scan3_pos_kernel<<<(N_EDGE + 255) / 256, 256, 0, stream>>>(
        excl, boff, row_ptr, src, dst, etype, off, einfo);

    att_dot_kernel<<<((N_EDGE + 63) / 64 * 64 + 255) / 256, 256, 0, stream>>>(
        ent_pi, Z, einfo, es_csr, N_EDGE);

    const int aggGrid = (N_ENT + 3) / 4;
    const int mlpGrid = 782;

    // ---- layer 0: agg with fused softmax stats ----
    agg64s_kernel<<<aggGrid, 256, 0, stream>>>(ent_pi, es_csr, row_ptr, stats, N_h, N_ENT);
    mlp_mfma_kernel<64, 64, true><<<mlpGrid, 256, 0, stream>>>(
        ent_pi, N_h, W1_0, b1_0, W2_0, b2_0, h1, out, 64);

    // ---- layer 1: D_IN=64 (h1) -> D_OUT=32 (h2) ----
    agg64_kernel<<<aggGrid, 256, 0, stream>>>(h1, es_csr, row_ptr, stats, N_h, N_ENT);
    mlp_mfma_kernel<64, 32, false><<<mlpGrid, 256, 0, stream>>>(
        h1, N_h, W1_1, b1_1, W2_1, b2_1, h2, out, 128);

    // ---- layer 2: D_IN=32 (h2) -> D_OUT=16 ----
    agg32_kernel<<<aggGrid, 256, 0, stream>>>(h2, es_csr, row_ptr, stats, N_h, N_ENT);
    mlp_mfma_kernel<32, 16, false><<<mlpGrid, 256, 0, stream>>>(
        h2, N_h, W1_2, b1_2, W2_2, b2_2, nullptr, out, 160);
}